// Round 2
// baseline (946.154 us; speedup 1.0000x reference)
//
#include <hip/hip_runtime.h>

// ---------------------------------------------------------------------------
// SABlock: x[4,1025,768] -> qkv proj -> masked attention (CSA block mask)
//          -> out proj + cls-attention top-k token selection.
// Round 2: out path fp32 (passing); cls_attn/top-k path fp64 end-to-end
//          (bottom-tail gaps ~1e-10 demand it; fuse ordering failed in fp32).
//
// Output layout in d_out (flat f32, reference tuple order):
//   out           [4,1025,768]  @ 0
//   enhance_index [4,103,768]   @ 3148800   (float-cast ints)
//   enh_idx       [4,103]       @ 3465216
//   fuse_index    [4,103,768]   @ 3465628
//   fuse_idx      [4,103]       @ 3782044
//   cls_attn      [4,1024]      @ 3782456
// ---------------------------------------------------------------------------

#define B_  4
#define N_  1025
#define C_  768
#define H_  12
#define D_  64
#define M_TOT (B_ * N_)      // 4100
#define QKV_O (3 * C_)       // 2304

#define OFF_OUT  0
#define OFF_EIND 3148800
#define OFF_EIDX 3465216
#define OFF_FIND 3465628
#define OFF_FIDX 3782044
#define OFF_CLS  3782456

// workspace offsets (in floats); PHD is a double array at float offset 12595200
#define WS_Q   0
#define WS_K   3148800
#define WS_V   6297600
#define WS_CTX 9446400
#define WS_PHD 12595200      // double[4][12][1024] per-head cls probs (393 KB)

// ---------------------------------------------------------------------------
// GEMM 1: qkv = x @ w_qkv^T, scattered to q/k/v in [b,h,n,d] layout.
// q is pre-scaled by 0.125 (exact pow2 -> bit-identical to scaling scores).
// ---------------------------------------------------------------------------
__global__ __launch_bounds__(256) void qkv_gemm_kernel(
    const float* __restrict__ x, const float* __restrict__ w,
    float* __restrict__ q, float* __restrict__ k, float* __restrict__ v)
{
    __shared__ float As[32][68];
    __shared__ float Bs[32][68];
    const int o0 = blockIdx.x * 64;
    const int m0 = blockIdx.y * 64;
    const int t  = threadIdx.x;
    const int tx = t & 15, ty = t >> 4;
    const int lr = t >> 2;
    const int lk = (t & 3) * 8;

    float acc[4][4];
    #pragma unroll
    for (int i = 0; i < 4; i++)
        #pragma unroll
        for (int j = 0; j < 4; j++) acc[i][j] = 0.f;

    const int m_ld = m0 + lr;
    const bool mval = (m_ld < M_TOT);
    const float* xsrc = x + (size_t)m_ld * C_ + lk;
    const float* wsrc = w + (size_t)(o0 + lr) * C_ + lk;

    for (int kb = 0; kb < C_; kb += 32) {
        float4 a0 = make_float4(0.f,0.f,0.f,0.f), a1 = a0;
        if (mval) { a0 = *(const float4*)(xsrc + kb); a1 = *(const float4*)(xsrc + kb + 4); }
        float4 b0 = *(const float4*)(wsrc + kb);
        float4 b1 = *(const float4*)(wsrc + kb + 4);
        As[lk+0][lr]=a0.x; As[lk+1][lr]=a0.y; As[lk+2][lr]=a0.z; As[lk+3][lr]=a0.w;
        As[lk+4][lr]=a1.x; As[lk+5][lr]=a1.y; As[lk+6][lr]=a1.z; As[lk+7][lr]=a1.w;
        Bs[lk+0][lr]=b0.x; Bs[lk+1][lr]=b0.y; Bs[lk+2][lr]=b0.z; Bs[lk+3][lr]=b0.w;
        Bs[lk+4][lr]=b1.x; Bs[lk+5][lr]=b1.y; Bs[lk+6][lr]=b1.z; Bs[lk+7][lr]=b1.w;
        __syncthreads();
        #pragma unroll
        for (int kk = 0; kk < 32; kk++) {
            float4 a4 = *(const float4*)&As[kk][ty*4];
            float4 b4 = *(const float4*)&Bs[kk][tx*4];
            acc[0][0]+=a4.x*b4.x; acc[0][1]+=a4.x*b4.y; acc[0][2]+=a4.x*b4.z; acc[0][3]+=a4.x*b4.w;
            acc[1][0]+=a4.y*b4.x; acc[1][1]+=a4.y*b4.y; acc[1][2]+=a4.y*b4.z; acc[1][3]+=a4.y*b4.w;
            acc[2][0]+=a4.z*b4.x; acc[2][1]+=a4.z*b4.y; acc[2][2]+=a4.z*b4.z; acc[2][3]+=a4.z*b4.w;
            acc[3][0]+=a4.w*b4.x; acc[3][1]+=a4.w*b4.y; acc[3][2]+=a4.w*b4.z; acc[3][3]+=a4.w*b4.w;
        }
        __syncthreads();
    }

    const int sel = o0 / C_;
    const int hh  = (o0 % C_) >> 6;
    float* dst = (sel == 0) ? q : (sel == 1) ? k : v;
    const float scl = (sel == 0) ? 0.125f : 1.0f;
    #pragma unroll
    for (int i = 0; i < 4; i++) {
        int m = m0 + ty*4 + i;
        if (m < M_TOT) {
            int bb = m / N_;
            int n  = m - bb * N_;
            float4 o;
            o.x = acc[i][0]*scl; o.y = acc[i][1]*scl; o.z = acc[i][2]*scl; o.w = acc[i][3]*scl;
            *(float4*)&dst[(((size_t)(bb*H_ + hh))*N_ + n)*D_ + tx*4] = o;
        }
    }
}

// ---------------------------------------------------------------------------
// Flash-style attention per (qtile, h, b). 64 queries x 17 key-tiles of 64.
// ---------------------------------------------------------------------------
__global__ __launch_bounds__(256) void attn_kernel(
    const float* __restrict__ qp, const float* __restrict__ kp,
    const float* __restrict__ vp, float* __restrict__ ctxp)
{
    __shared__ float Qt[64][68];
    __shared__ float KPs[64][68];
    __shared__ float Vs[64][68];
    const int qt = blockIdx.x, h = blockIdx.y, b = blockIdx.z;
    const int t  = threadIdx.x;
    const int tx = t & 15, ty = t >> 4;
    const int lr = t >> 2, ld = (t & 3) * 16;
    const size_t base = ((size_t)(b*H_ + h)) * (N_ * D_);

    {
        int n = qt*64 + lr;
        if (n < N_) {
            const float* src = qp + base + (size_t)n*D_ + ld;
            #pragma unroll
            for (int e = 0; e < 4; e++) {
                float4 f = *(const float4*)(src + e*4);
                Qt[ld+e*4+0][lr] = f.x; Qt[ld+e*4+1][lr] = f.y;
                Qt[ld+e*4+2][lr] = f.z; Qt[ld+e*4+3][lr] = f.w;
            }
        } else {
            #pragma unroll
            for (int e = 0; e < 16; e++) Qt[ld+e][lr] = 0.f;
        }
    }

    float m_run[4], l_run[4], ctxa[4][4];
    #pragma unroll
    for (int i = 0; i < 4; i++) {
        m_run[i] = -1e30f; l_run[i] = 0.f;
        #pragma unroll
        for (int j = 0; j < 4; j++) ctxa[i][j] = 0.f;
    }
    const int row0 = qt*64 + ty*4;

    for (int kt = 0; kt < 17; kt++) {
        __syncthreads();
        {
            int n = kt*64 + lr;
            if (n < N_) {
                const float* ks = kp + base + (size_t)n*D_ + ld;
                const float* vs = vp + base + (size_t)n*D_ + ld;
                #pragma unroll
                for (int e = 0; e < 4; e++) {
                    float4 f = *(const float4*)(ks + e*4);
                    KPs[ld+e*4+0][lr] = f.x; KPs[ld+e*4+1][lr] = f.y;
                    KPs[ld+e*4+2][lr] = f.z; KPs[ld+e*4+3][lr] = f.w;
                    float4 g = *(const float4*)(vs + e*4);
                    *(float4*)&Vs[lr][ld + e*4] = g;
                }
            } else {
                #pragma unroll
                for (int e = 0; e < 16; e++) KPs[ld+e][lr] = 0.f;
                #pragma unroll
                for (int e = 0; e < 4; e++)
                    *(float4*)&Vs[lr][ld + e*4] = make_float4(0.f,0.f,0.f,0.f);
            }
        }
        __syncthreads();

        float s[4][4];
        #pragma unroll
        for (int i = 0; i < 4; i++)
            #pragma unroll
            for (int j = 0; j < 4; j++) s[i][j] = 0.f;
        #pragma unroll 8
        for (int d = 0; d < 64; d++) {
            float4 a4 = *(const float4*)&Qt[d][ty*4];
            float4 b4 = *(const float4*)&KPs[d][tx*4];
            s[0][0]+=a4.x*b4.x; s[0][1]+=a4.x*b4.y; s[0][2]+=a4.x*b4.z; s[0][3]+=a4.x*b4.w;
            s[1][0]+=a4.y*b4.x; s[1][1]+=a4.y*b4.y; s[1][2]+=a4.y*b4.z; s[1][3]+=a4.y*b4.w;
            s[2][0]+=a4.z*b4.x; s[2][1]+=a4.z*b4.y; s[2][2]+=a4.z*b4.z; s[2][3]+=a4.z*b4.w;
            s[3][0]+=a4.w*b4.x; s[3][1]+=a4.w*b4.y; s[3][2]+=a4.w*b4.z; s[3][3]+=a4.w*b4.w;
        }

        const int col0 = kt*64 + tx*4;
        #pragma unroll
        for (int i = 0; i < 4; i++) {
            int ig = row0 + i;
            int mybid = (ig >= 1) ? ((ig - 1) >> 8) : -1;
            float mloc = -1e30f;
            #pragma unroll
            for (int j = 0; j < 4; j++) {
                int jg = col0 + j;
                bool ok = (jg < N_) &&
                          !((ig >= 1) && (jg >= 1) && (((jg - 1) >> 8) == mybid));
                s[i][j] = ok ? s[i][j] : -1e30f;
                mloc = fmaxf(mloc, s[i][j]);
            }
            mloc = fmaxf(mloc, __shfl_xor(mloc, 1));
            mloc = fmaxf(mloc, __shfl_xor(mloc, 2));
            mloc = fmaxf(mloc, __shfl_xor(mloc, 4));
            mloc = fmaxf(mloc, __shfl_xor(mloc, 8));
            float mnew  = fmaxf(m_run[i], mloc);
            float alpha = __expf(m_run[i] - mnew);
            m_run[i] = mnew;
            float psum = 0.f;
            #pragma unroll
            for (int j = 0; j < 4; j++) {
                float p = (s[i][j] > -1e29f) ? __expf(s[i][j] - mnew) : 0.f;
                s[i][j] = p; psum += p;
            }
            psum += __shfl_xor(psum, 1);
            psum += __shfl_xor(psum, 2);
            psum += __shfl_xor(psum, 4);
            psum += __shfl_xor(psum, 8);
            l_run[i] = l_run[i] * alpha + psum;
            #pragma unroll
            for (int j = 0; j < 4; j++) ctxa[i][j] *= alpha;
        }

        __syncthreads();
        #pragma unroll
        for (int i = 0; i < 4; i++)
            #pragma unroll
            for (int j = 0; j < 4; j++)
                KPs[ty*4 + i][tx*4 + j] = s[i][j];
        __syncthreads();

        #pragma unroll 8
        for (int j = 0; j < 64; j++) {
            float4 b4 = *(const float4*)&Vs[j][tx*4];
            float a0 = KPs[ty*4+0][j], a1 = KPs[ty*4+1][j];
            float a2 = KPs[ty*4+2][j], a3 = KPs[ty*4+3][j];
            ctxa[0][0]+=a0*b4.x; ctxa[0][1]+=a0*b4.y; ctxa[0][2]+=a0*b4.z; ctxa[0][3]+=a0*b4.w;
            ctxa[1][0]+=a1*b4.x; ctxa[1][1]+=a1*b4.y; ctxa[1][2]+=a1*b4.z; ctxa[1][3]+=a1*b4.w;
            ctxa[2][0]+=a2*b4.x; ctxa[2][1]+=a2*b4.y; ctxa[2][2]+=a2*b4.z; ctxa[2][3]+=a2*b4.w;
            ctxa[3][0]+=a3*b4.x; ctxa[3][1]+=a3*b4.y; ctxa[3][2]+=a3*b4.z; ctxa[3][3]+=a3*b4.w;
        }
    }

    #pragma unroll
    for (int i = 0; i < 4; i++) {
        int n = row0 + i;
        if (n < N_) {
            float inv = 1.0f / l_run[i];
            float4 o;
            o.x = ctxa[i][0]*inv; o.y = ctxa[i][1]*inv;
            o.z = ctxa[i][2]*inv; o.w = ctxa[i][3]*inv;
            *(float4*)&ctxp[((size_t)(b*N_ + n))*C_ + h*D_ + tx*4] = o;
        }
    }
}

// ---------------------------------------------------------------------------
// cls path, fp64 end-to-end per (h, b).
// logit_j = x_j . (Wk^T (Wq x0) * scale)  -- projections collapsed, so only
// ~0.8M fp64 MACs per block instead of materializing K in fp64.
// Softmax fp64; per-head probs written to phd (no atomics -> deterministic).
// ---------------------------------------------------------------------------
__global__ __launch_bounds__(256) void cls_f64_kernel(
    const float* __restrict__ x, const float* __restrict__ w_qkv,
    double* __restrict__ phd)
{
    const int h = blockIdx.x, b = blockIdx.y;
    __shared__ float  x0s[768];
    __shared__ double q0s[64];
    __shared__ double ms[768];
    __shared__ double lg[1025];
    __shared__ double red[256];
    const int t = threadIdx.x;
    const float* xb = x + (size_t)b * N_ * C_;

    for (int c = t; c < C_; c += 256) x0s[c] = xb[c];
    __syncthreads();

    if (t < 64) {                       // q0_d = (x0 . Wq_row) * 0.125
        const float* wr = w_qkv + (size_t)(h*64 + t) * C_;
        double s = 0.0;
        for (int c = 0; c < C_; c++) s += (double)x0s[c] * (double)wr[c];
        q0s[t] = s * 0.125;
    }
    __syncthreads();

    for (int c = t; c < C_; c += 256) { // m_c = sum_d q0_d * Wk[h*64+d, c]
        const float* wk = w_qkv + (size_t)(C_ + h*64) * C_ + c;
        double s = 0.0;
        #pragma unroll 8
        for (int d = 0; d < 64; d++) s += q0s[d] * (double)wk[(size_t)d * C_];
        ms[c] = s;
    }
    __syncthreads();

    for (int j = t; j < N_; j += 256) { // logits
        const float* xr = xb + (size_t)j * C_;
        double s = 0.0;
        #pragma unroll 4
        for (int c = 0; c < C_; c++) s += (double)xr[c] * ms[c];
        lg[j] = s;
    }
    __syncthreads();

    double mloc = -1e300;
    for (int j = t; j < N_; j += 256) mloc = fmax(mloc, lg[j]);
    red[t] = mloc; __syncthreads();
    for (int o = 128; o > 0; o >>= 1) {
        if (t < o) red[t] = fmax(red[t], red[t+o]);
        __syncthreads();
    }
    double mx = red[0]; __syncthreads();

    double sloc = 0.0;
    for (int j = t; j < N_; j += 256) { double e = exp(lg[j] - mx); lg[j] = e; sloc += e; }
    red[t] = sloc; __syncthreads();
    for (int o = 128; o > 0; o >>= 1) {
        if (t < o) red[t] += red[t+o];
        __syncthreads();
    }
    double Z = red[0];

    for (int j = t; j < N_; j += 256)
        if (j >= 1) phd[((size_t)(b*H_ + h))*1024 + (j-1)] = lg[j] / Z;
}

// ---------------------------------------------------------------------------
// Per-batch: cls_attn = mean_h phd (fp64) -> d_out (f32); two bitonic sorts
// on fp64 keys (desc -> enh, asc -> fuse), jax.lax.top_k tie-break.
// ---------------------------------------------------------------------------
__global__ __launch_bounds__(256) void topk_kernel(
    const double* __restrict__ phd, float* __restrict__ out)
{
    const int b = blockIdx.x;
    __shared__ double cvals[1024];
    __shared__ double sval[1024];
    __shared__ int    sidx[1024];
    const int t = threadIdx.x;

    for (int i = t; i < 1024; i += 256) {
        double s = 0.0;
        #pragma unroll
        for (int h = 0; h < H_; h++) s += phd[((size_t)(b*H_ + h))*1024 + i];
        s = s / 12.0;
        cvals[i] = s;
        out[OFF_CLS + (size_t)b*1024 + i] = (float)s;
    }

    for (int pass = 0; pass < 2; pass++) {
        const bool desc = (pass == 0);
        __syncthreads();
        for (int i = t; i < 1024; i += 256) { sval[i] = cvals[i]; sidx[i] = i; }
        for (int k = 2; k <= 1024; k <<= 1) {
            for (int j = k >> 1; j > 0; j >>= 1) {
                __syncthreads();
                for (int i = t; i < 1024; i += 256) {
                    int l = i ^ j;
                    if (l > i) {
                        double av = sval[i], bv = sval[l];
                        int    ai = sidx[i], bi = sidx[l];
                        bool before = desc ? (av > bv || (av == bv && ai < bi))
                                           : (av < bv || (av == bv && ai < bi));
                        bool up = ((i & k) == 0);
                        if (up ? !before : before) {
                            sval[i] = bv; sval[l] = av;
                            sidx[i] = bi; sidx[l] = ai;
                        }
                    }
                }
            }
        }
        __syncthreads();
        const size_t idx_off = desc ? (size_t)OFF_EIDX : (size_t)OFF_FIDX;
        const size_t ind_off = desc ? (size_t)OFF_EIND : (size_t)OFF_FIND;
        if (t < 103) out[idx_off + (size_t)b*103 + t] = (float)sidx[t];
        for (int u = t*4; u < 103*768; u += 1024) {
            int e = u / 768;
            float fv = (float)sidx[e];
            *(float4*)&out[ind_off + (size_t)b*103*768 + u] = make_float4(fv, fv, fv, fv);
        }
    }
}

// ---------------------------------------------------------------------------
// GEMM 2: out = ctx @ w_out^T + b_out
// ---------------------------------------------------------------------------
__global__ __launch_bounds__(256) void out_gemm_kernel(
    const float* __restrict__ ctx, const float* __restrict__ w,
    const float* __restrict__ bias, float* __restrict__ out)
{
    __shared__ float As[32][68];
    __shared__ float Bs[32][68];
    const int o0 = blockIdx.x * 64;
    const int m0 = blockIdx.y * 64;
    const int t  = threadIdx.x;
    const int tx = t & 15, ty = t >> 4;
    const int lr = t >> 2;
    const int lk = (t & 3) * 8;

    float acc[4][4];
    #pragma unroll
    for (int i = 0; i < 4; i++)
        #pragma unroll
        for (int j = 0; j < 4; j++) acc[i][j] = 0.f;

    const int m_ld = m0 + lr;
    const bool mval = (m_ld < M_TOT);
    const float* xsrc = ctx + (size_t)m_ld * C_ + lk;
    const float* wsrc = w + (size_t)(o0 + lr) * C_ + lk;

    for (int kb = 0; kb < C_; kb += 32) {
        float4 a0 = make_float4(0.f,0.f,0.f,0.f), a1 = a0;
        if (mval) { a0 = *(const float4*)(xsrc + kb); a1 = *(const float4*)(xsrc + kb + 4); }
        float4 b0 = *(const float4*)(wsrc + kb);
        float4 b1 = *(const float4*)(wsrc + kb + 4);
        As[lk+0][lr]=a0.x; As[lk+1][lr]=a0.y; As[lk+2][lr]=a0.z; As[lk+3][lr]=a0.w;
        As[lk+4][lr]=a1.x; As[lk+5][lr]=a1.y; As[lk+6][lr]=a1.z; As[lk+7][lr]=a1.w;
        Bs[lk+0][lr]=b0.x; Bs[lk+1][lr]=b0.y; Bs[lk+2][lr]=b0.z; Bs[lk+3][lr]=b0.w;
        Bs[lk+4][lr]=b1.x; Bs[lk+5][lr]=b1.y; Bs[lk+6][lr]=b1.z; Bs[lk+7][lr]=b1.w;
        __syncthreads();
        #pragma unroll
        for (int kk = 0; kk < 32; kk++) {
            float4 a4 = *(const float4*)&As[kk][ty*4];
            float4 b4 = *(const float4*)&Bs[kk][tx*4];
            acc[0][0]+=a4.x*b4.x; acc[0][1]+=a4.x*b4.y; acc[0][2]+=a4.x*b4.z; acc[0][3]+=a4.x*b4.w;
            acc[1][0]+=a4.y*b4.x; acc[1][1]+=a4.y*b4.y; acc[1][2]+=a4.y*b4.z; acc[1][3]+=a4.y*b4.w;
            acc[2][0]+=a4.z*b4.x; acc[2][1]+=a4.z*b4.y; acc[2][2]+=a4.z*b4.z; acc[2][3]+=a4.z*b4.w;
            acc[3][0]+=a4.w*b4.x; acc[3][1]+=a4.w*b4.y; acc[3][2]+=a4.w*b4.z; acc[3][3]+=a4.w*b4.w;
        }
        __syncthreads();
    }

    float4 bia = *(const float4*)&bias[o0 + tx*4];
    #pragma unroll
    for (int i = 0; i < 4; i++) {
        int m = m0 + ty*4 + i;
        if (m < M_TOT) {
            float4 o;
            o.x = acc[i][0] + bia.x; o.y = acc[i][1] + bia.y;
            o.z = acc[i][2] + bia.z; o.w = acc[i][3] + bia.w;
            *(float4*)&out[(size_t)m * C_ + o0 + tx*4] = o;
        }
    }
}

// ---------------------------------------------------------------------------
extern "C" void kernel_launch(void* const* d_in, const int* in_sizes, int n_in,
                              void* d_out, int out_size, void* d_ws, size_t ws_size,
                              hipStream_t stream)
{
    const float* x     = (const float*)d_in[0];
    const float* w_qkv = (const float*)d_in[1];
    const float* w_out = (const float*)d_in[2];
    const float* b_out = (const float*)d_in[3];
    float* out = (float*)d_out;
    float* ws  = (float*)d_ws;

    float*  q   = ws + WS_Q;
    float*  k   = ws + WS_K;
    float*  v   = ws + WS_V;
    float*  ctx = ws + WS_CTX;
    double* phd = (double*)(ws + WS_PHD);

    qkv_gemm_kernel<<<dim3(QKV_O/64, (M_TOT + 63)/64), 256, 0, stream>>>(x, w_qkv, q, k, v);
    attn_kernel<<<dim3(17, H_, B_), 256, 0, stream>>>(q, k, v, ctx);
    cls_f64_kernel<<<dim3(H_, B_), 256, 0, stream>>>(x, w_qkv, phd);
    topk_kernel<<<B_, 256, 0, stream>>>(phd, out);
    out_gemm_kernel<<<dim3(C_/64, (M_TOT + 63)/64), 256, 0, stream>>>(ctx, w_out, b_out, out);
}

// Round 3
// 819.467 us; speedup vs baseline: 1.1546x; 1.1546x over previous
//
#include <hip/hip_runtime.h>

// ---------------------------------------------------------------------------
// SABlock round 3: GEMMs moved to bf16 MFMA via split-bf16 K-expansion
//   A' = [Ah | Ah | Al]  (K 768 -> 2304)
//   B' = [Bh | Bl | Bh]
//   A'.B'^T = Ah.Bh + Ah.Bl + Al.Bh  ~= A.B with rel err ~2^-16 (fp32-like).
// attn stays fp32 (next round); cls/topk stay fp64 (index exactness).
//
// d_out layout (flat f32): out@0, enh_index@3148800, enh_idx@3465216,
//   fuse_index@3465628, fuse_idx@3782044, cls_attn@3782456
// ---------------------------------------------------------------------------

#define B_  4
#define N_  1025
#define C_  768
#define H_  12
#define D_  64
#define M_TOT (B_ * N_)      // 4100
#define M_PAD 4224           // 33 * 128
#define KEXP 2304            // 3 * 768

#define OFF_EIND 3148800
#define OFF_EIDX 3465216
#define OFF_FIND 3465628
#define OFF_FIDX 3782044
#define OFF_CLS  3782456

// workspace offsets (floats); total high-water 21196800 f = 84.8 MB
#define WS_Q     0
#define WS_K     3148800
#define WS_V     6297600
#define WS_CTX   9446400
#define WS_PHD   12595200    // double[4*12*1024]
#define WS_XS    12791808    // ushort[4224*2304]  (A' of x; reused for ctx')
#define WS_QKVB  17657856    // ushort[2304*2304]  (B' of w_qkv)
#define WS_OUTB  20312064    // ushort[768*2304]   (B' of w_out)

typedef short s16x8 __attribute__((ext_vector_type(8)));
typedef float f32x4 __attribute__((ext_vector_type(4)));

__device__ inline unsigned short f2bf(float f) {
    unsigned u = __float_as_uint(f);
    u += 0x7FFF + ((u >> 16) & 1);          // RNE to bf16
    return (unsigned short)(u >> 16);
}
__device__ inline float bf2f(unsigned short h) {
    return __uint_as_float(((unsigned)h) << 16);
}

// ---------------------------------------------------------------------------
// Splitters: fp32 [M x 768] -> ushort bf16 [Mpad x 2304]
//   A-pattern: [hi | hi | lo]   B-pattern: [hi | lo | hi]
// ---------------------------------------------------------------------------
__global__ __launch_bounds__(256) void split_a_kernel(
    const float* __restrict__ src, unsigned short* __restrict__ dst,
    int M, int Mpad)
{
    int idx = blockIdx.x * 256 + threadIdx.x;     // over Mpad*192
    int m = idx / 192, c4 = (idx - m * 192) * 4;
    if (m >= Mpad) return;
    ushort4 hi = make_ushort4(0,0,0,0), lo = hi;
    if (m < M) {
        float4 f = *(const float4*)&src[(size_t)m * C_ + c4];
        hi.x = f2bf(f.x); hi.y = f2bf(f.y); hi.z = f2bf(f.z); hi.w = f2bf(f.w);
        lo.x = f2bf(f.x - bf2f(hi.x)); lo.y = f2bf(f.y - bf2f(hi.y));
        lo.z = f2bf(f.z - bf2f(hi.z)); lo.w = f2bf(f.w - bf2f(hi.w));
    }
    unsigned short* d = dst + (size_t)m * KEXP + c4;
    *(ushort4*)(d)        = hi;
    *(ushort4*)(d + 768)  = hi;
    *(ushort4*)(d + 1536) = lo;
}

__global__ __launch_bounds__(256) void split_b_kernel(
    const float* __restrict__ src, unsigned short* __restrict__ dst, int M)
{
    int idx = blockIdx.x * 256 + threadIdx.x;     // over M*192
    int m = idx / 192, c4 = (idx - m * 192) * 4;
    if (m >= M) return;
    float4 f = *(const float4*)&src[(size_t)m * C_ + c4];
    ushort4 hi, lo;
    hi.x = f2bf(f.x); hi.y = f2bf(f.y); hi.z = f2bf(f.z); hi.w = f2bf(f.w);
    lo.x = f2bf(f.x - bf2f(hi.x)); lo.y = f2bf(f.y - bf2f(hi.y));
    lo.z = f2bf(f.z - bf2f(hi.z)); lo.w = f2bf(f.w - bf2f(hi.w));
    unsigned short* d = dst + (size_t)m * KEXP + c4;
    *(ushort4*)(d)        = hi;
    *(ushort4*)(d + 768)  = lo;
    *(ushort4*)(d + 1536) = hi;
}

// ---------------------------------------------------------------------------
// bf16 MFMA GEMM, C = A'.B'^T. Tile 128x128, BK=32, 4 waves (2x2 of 64x64).
// MFMA 16x16x32: A[m=lane&15][k=quad*8+j]; C/D col=lane&15,row=quad*4+reg.
// qkv variant scatters to q/k/v [b,h,n,d] (q * 0.125).
// ---------------------------------------------------------------------------
__global__ __launch_bounds__(256) void gemm_qkv_kernel(
    const unsigned short* __restrict__ A, const unsigned short* __restrict__ Bm,
    float* __restrict__ q, float* __restrict__ k, float* __restrict__ v)
{
    __shared__ unsigned short As[128][40];   // 40-el (80B) rows: conflict-free b128
    __shared__ unsigned short Bs[128][40];
    const int n0 = blockIdx.x * 128;
    const int m0 = blockIdx.y * 128;
    const int t = threadIdx.x;
    const int lane = t & 63, wv = t >> 6;
    const int wr = wv >> 1, wc = wv & 1;
    const int q4 = lane >> 4, r = lane & 15;
    const int srow = t >> 2, scol = (t & 3) * 8;

    f32x4 acc[4][4];
    #pragma unroll
    for (int i = 0; i < 4; i++)
        #pragma unroll
        for (int j = 0; j < 4; j++)
            #pragma unroll
            for (int e = 0; e < 4; e++) acc[i][j][e] = 0.f;

    const unsigned short* a0p = A  + (size_t)(m0 + srow) * KEXP + scol;
    const unsigned short* b0p = Bm + (size_t)(n0 + srow) * KEXP + scol;

    for (int kb = 0; kb < KEXP; kb += 32) {
        uint4 va0 = *(const uint4*)(a0p + kb);
        uint4 va1 = *(const uint4*)(a0p + kb + (size_t)64 * KEXP);
        uint4 vb0 = *(const uint4*)(b0p + kb);
        uint4 vb1 = *(const uint4*)(b0p + kb + (size_t)64 * KEXP);
        __syncthreads();
        *(uint4*)&As[srow][scol]      = va0;
        *(uint4*)&As[srow + 64][scol] = va1;
        *(uint4*)&Bs[srow][scol]      = vb0;
        *(uint4*)&Bs[srow + 64][scol] = vb1;
        __syncthreads();
        s16x8 af[4], bfr[4];
        #pragma unroll
        for (int i = 0; i < 4; i++) {
            af[i]  = *(const s16x8*)&As[wr*64 + i*16 + r][q4*8];
            bfr[i] = *(const s16x8*)&Bs[wc*64 + i*16 + r][q4*8];
        }
        #pragma unroll
        for (int i = 0; i < 4; i++)
            #pragma unroll
            for (int j = 0; j < 4; j++)
                acc[i][j] = __builtin_amdgcn_mfma_f32_16x16x32_bf16(af[i], bfr[j], acc[i][j], 0, 0, 0);
    }

    const int sel = n0 / C_;
    const int off = n0 % C_;
    float* dst = (sel == 0) ? q : (sel == 1) ? k : v;
    const float scl = (sel == 0) ? 0.125f : 1.0f;
    #pragma unroll
    for (int i = 0; i < 4; i++) {
        #pragma unroll
        for (int rr = 0; rr < 4; rr++) {
            int gm = m0 + wr*64 + i*16 + q4*4 + rr;
            if (gm < M_TOT) {
                int bb = gm / N_, n = gm - bb * N_;
                #pragma unroll
                for (int j = 0; j < 4; j++) {
                    int col = off + wc*64 + j*16 + r;
                    int h = col >> 6, d = col & 63;
                    dst[(((size_t)(bb*H_ + h))*N_ + n)*D_ + d] = acc[i][j][rr] * scl;
                }
            }
        }
    }
}

__global__ __launch_bounds__(256) void gemm_out_kernel(
    const unsigned short* __restrict__ A, const unsigned short* __restrict__ Bm,
    const float* __restrict__ bias, float* __restrict__ out)
{
    __shared__ unsigned short As[128][40];
    __shared__ unsigned short Bs[128][40];
    const int n0 = blockIdx.x * 128;
    const int m0 = blockIdx.y * 128;
    const int t = threadIdx.x;
    const int lane = t & 63, wv = t >> 6;
    const int wr = wv >> 1, wc = wv & 1;
    const int q4 = lane >> 4, r = lane & 15;
    const int srow = t >> 2, scol = (t & 3) * 8;

    f32x4 acc[4][4];
    #pragma unroll
    for (int i = 0; i < 4; i++)
        #pragma unroll
        for (int j = 0; j < 4; j++)
            #pragma unroll
            for (int e = 0; e < 4; e++) acc[i][j][e] = 0.f;

    const unsigned short* a0p = A  + (size_t)(m0 + srow) * KEXP + scol;
    const unsigned short* b0p = Bm + (size_t)(n0 + srow) * KEXP + scol;

    for (int kb = 0; kb < KEXP; kb += 32) {
        uint4 va0 = *(const uint4*)(a0p + kb);
        uint4 va1 = *(const uint4*)(a0p + kb + (size_t)64 * KEXP);
        uint4 vb0 = *(const uint4*)(b0p + kb);
        uint4 vb1 = *(const uint4*)(b0p + kb + (size_t)64 * KEXP);
        __syncthreads();
        *(uint4*)&As[srow][scol]      = va0;
        *(uint4*)&As[srow + 64][scol] = va1;
        *(uint4*)&Bs[srow][scol]      = vb0;
        *(uint4*)&Bs[srow + 64][scol] = vb1;
        __syncthreads();
        s16x8 af[4], bfr[4];
        #pragma unroll
        for (int i = 0; i < 4; i++) {
            af[i]  = *(const s16x8*)&As[wr*64 + i*16 + r][q4*8];
            bfr[i] = *(const s16x8*)&Bs[wc*64 + i*16 + r][q4*8];
        }
        #pragma unroll
        for (int i = 0; i < 4; i++)
            #pragma unroll
            for (int j = 0; j < 4; j++)
                acc[i][j] = __builtin_amdgcn_mfma_f32_16x16x32_bf16(af[i], bfr[j], acc[i][j], 0, 0, 0);
    }

    #pragma unroll
    for (int i = 0; i < 4; i++) {
        #pragma unroll
        for (int rr = 0; rr < 4; rr++) {
            int gm = m0 + wr*64 + i*16 + q4*4 + rr;
            if (gm < M_TOT) {
                #pragma unroll
                for (int j = 0; j < 4; j++) {
                    int col = n0 + wc*64 + j*16 + r;
                    out[(size_t)gm * C_ + col] = acc[i][j][rr] + bias[col];
                }
            }
        }
    }
}

// ---------------------------------------------------------------------------
// Flash-style fp32 attention (unchanged, passing).
// ---------------------------------------------------------------------------
__global__ __launch_bounds__(256) void attn_kernel(
    const float* __restrict__ qp, const float* __restrict__ kp,
    const float* __restrict__ vp, float* __restrict__ ctxp)
{
    __shared__ float Qt[64][68];
    __shared__ float KPs[64][68];
    __shared__ float Vs[64][68];
    const int qt = blockIdx.x, h = blockIdx.y, b = blockIdx.z;
    const int t  = threadIdx.x;
    const int tx = t & 15, ty = t >> 4;
    const int lr = t >> 2, ld = (t & 3) * 16;
    const size_t base = ((size_t)(b*H_ + h)) * (N_ * D_);

    {
        int n = qt*64 + lr;
        if (n < N_) {
            const float* src = qp + base + (size_t)n*D_ + ld;
            #pragma unroll
            for (int e = 0; e < 4; e++) {
                float4 f = *(const float4*)(src + e*4);
                Qt[ld+e*4+0][lr] = f.x; Qt[ld+e*4+1][lr] = f.y;
                Qt[ld+e*4+2][lr] = f.z; Qt[ld+e*4+3][lr] = f.w;
            }
        } else {
            #pragma unroll
            for (int e = 0; e < 16; e++) Qt[ld+e][lr] = 0.f;
        }
    }

    float m_run[4], l_run[4], ctxa[4][4];
    #pragma unroll
    for (int i = 0; i < 4; i++) {
        m_run[i] = -1e30f; l_run[i] = 0.f;
        #pragma unroll
        for (int j = 0; j < 4; j++) ctxa[i][j] = 0.f;
    }
    const int row0 = qt*64 + ty*4;

    for (int kt = 0; kt < 17; kt++) {
        __syncthreads();
        {
            int n = kt*64 + lr;
            if (n < N_) {
                const float* ks = kp + base + (size_t)n*D_ + ld;
                const float* vs = vp + base + (size_t)n*D_ + ld;
                #pragma unroll
                for (int e = 0; e < 4; e++) {
                    float4 f = *(const float4*)(ks + e*4);
                    KPs[ld+e*4+0][lr] = f.x; KPs[ld+e*4+1][lr] = f.y;
                    KPs[ld+e*4+2][lr] = f.z; KPs[ld+e*4+3][lr] = f.w;
                    float4 g = *(const float4*)(vs + e*4);
                    *(float4*)&Vs[lr][ld + e*4] = g;
                }
            } else {
                #pragma unroll
                for (int e = 0; e < 16; e++) KPs[ld+e][lr] = 0.f;
                #pragma unroll
                for (int e = 0; e < 4; e++)
                    *(float4*)&Vs[lr][ld + e*4] = make_float4(0.f,0.f,0.f,0.f);
            }
        }
        __syncthreads();

        float s[4][4];
        #pragma unroll
        for (int i = 0; i < 4; i++)
            #pragma unroll
            for (int j = 0; j < 4; j++) s[i][j] = 0.f;
        #pragma unroll 8
        for (int d = 0; d < 64; d++) {
            float4 a4 = *(const float4*)&Qt[d][ty*4];
            float4 b4 = *(const float4*)&KPs[d][tx*4];
            s[0][0]+=a4.x*b4.x; s[0][1]+=a4.x*b4.y; s[0][2]+=a4.x*b4.z; s[0][3]+=a4.x*b4.w;
            s[1][0]+=a4.y*b4.x; s[1][1]+=a4.y*b4.y; s[1][2]+=a4.y*b4.z; s[1][3]+=a4.y*b4.w;
            s[2][0]+=a4.z*b4.x; s[2][1]+=a4.z*b4.y; s[2][2]+=a4.z*b4.z; s[2][3]+=a4.z*b4.w;
            s[3][0]+=a4.w*b4.x; s[3][1]+=a4.w*b4.y; s[3][2]+=a4.w*b4.z; s[3][3]+=a4.w*b4.w;
        }

        const int col0 = kt*64 + tx*4;
        #pragma unroll
        for (int i = 0; i < 4; i++) {
            int ig = row0 + i;
            int mybid = (ig >= 1) ? ((ig - 1) >> 8) : -1;
            float mloc = -1e30f;
            #pragma unroll
            for (int j = 0; j < 4; j++) {
                int jg = col0 + j;
                bool ok = (jg < N_) &&
                          !((ig >= 1) && (jg >= 1) && (((jg - 1) >> 8) == mybid));
                s[i][j] = ok ? s[i][j] : -1e30f;
                mloc = fmaxf(mloc, s[i][j]);
            }
            mloc = fmaxf(mloc, __shfl_xor(mloc, 1));
            mloc = fmaxf(mloc, __shfl_xor(mloc, 2));
            mloc = fmaxf(mloc, __shfl_xor(mloc, 4));
            mloc = fmaxf(mloc, __shfl_xor(mloc, 8));
            float mnew  = fmaxf(m_run[i], mloc);
            float alpha = __expf(m_run[i] - mnew);
            m_run[i] = mnew;
            float psum = 0.f;
            #pragma unroll
            for (int j = 0; j < 4; j++) {
                float p = (s[i][j] > -1e29f) ? __expf(s[i][j] - mnew) : 0.f;
                s[i][j] = p; psum += p;
            }
            psum += __shfl_xor(psum, 1);
            psum += __shfl_xor(psum, 2);
            psum += __shfl_xor(psum, 4);
            psum += __shfl_xor(psum, 8);
            l_run[i] = l_run[i] * alpha + psum;
            #pragma unroll
            for (int j = 0; j < 4; j++) ctxa[i][j] *= alpha;
        }

        __syncthreads();
        #pragma unroll
        for (int i = 0; i < 4; i++)
            #pragma unroll
            for (int j = 0; j < 4; j++)
                KPs[ty*4 + i][tx*4 + j] = s[i][j];
        __syncthreads();

        #pragma unroll 8
        for (int j = 0; j < 64; j++) {
            float4 b4 = *(const float4*)&Vs[j][tx*4];
            float a0 = KPs[ty*4+0][j], a1 = KPs[ty*4+1][j];
            float a2 = KPs[ty*4+2][j], a3 = KPs[ty*4+3][j];
            ctxa[0][0]+=a0*b4.x; ctxa[0][1]+=a0*b4.y; ctxa[0][2]+=a0*b4.z; ctxa[0][3]+=a0*b4.w;
            ctxa[1][0]+=a1*b4.x; ctxa[1][1]+=a1*b4.y; ctxa[1][2]+=a1*b4.z; ctxa[1][3]+=a1*b4.w;
            ctxa[2][0]+=a2*b4.x; ctxa[2][1]+=a2*b4.y; ctxa[2][2]+=a2*b4.z; ctxa[2][3]+=a2*b4.w;
            ctxa[3][0]+=a3*b4.x; ctxa[3][1]+=a3*b4.y; ctxa[3][2]+=a3*b4.z; ctxa[3][3]+=a3*b4.w;
        }
    }

    #pragma unroll
    for (int i = 0; i < 4; i++) {
        int n = row0 + i;
        if (n < N_) {
            float inv = 1.0f / l_run[i];
            float4 o;
            o.x = ctxa[i][0]*inv; o.y = ctxa[i][1]*inv;
            o.z = ctxa[i][2]*inv; o.w = ctxa[i][3]*inv;
            *(float4*)&ctxp[((size_t)(b*N_ + n))*C_ + h*D_ + tx*4] = o;
        }
    }
}

// ---------------------------------------------------------------------------
// cls path fp64 (unchanged, passing) + topk (unchanged, passing).
// ---------------------------------------------------------------------------
__global__ __launch_bounds__(256) void cls_f64_kernel(
    const float* __restrict__ x, const float* __restrict__ w_qkv,
    double* __restrict__ phd)
{
    const int h = blockIdx.x, b = blockIdx.y;
    __shared__ float  x0s[768];
    __shared__ double q0s[64];
    __shared__ double ms[768];
    __shared__ double lg[1025];
    __shared__ double red[256];
    const int t = threadIdx.x;
    const float* xb = x + (size_t)b * N_ * C_;

    for (int c = t; c < C_; c += 256) x0s[c] = xb[c];
    __syncthreads();

    if (t < 64) {
        const float* wr = w_qkv + (size_t)(h*64 + t) * C_;
        double s = 0.0;
        for (int c = 0; c < C_; c++) s += (double)x0s[c] * (double)wr[c];
        q0s[t] = s * 0.125;
    }
    __syncthreads();

    for (int c = t; c < C_; c += 256) {
        const float* wk = w_qkv + (size_t)(C_ + h*64) * C_ + c;
        double s = 0.0;
        #pragma unroll 8
        for (int d = 0; d < 64; d++) s += q0s[d] * (double)wk[(size_t)d * C_];
        ms[c] = s;
    }
    __syncthreads();

    for (int j = t; j < N_; j += 256) {
        const float* xr = xb + (size_t)j * C_;
        double s = 0.0;
        #pragma unroll 4
        for (int c = 0; c < C_; c++) s += (double)xr[c] * ms[c];
        lg[j] = s;
    }
    __syncthreads();

    double mloc = -1e300;
    for (int j = t; j < N_; j += 256) mloc = fmax(mloc, lg[j]);
    red[t] = mloc; __syncthreads();
    for (int o = 128; o > 0; o >>= 1) {
        if (t < o) red[t] = fmax(red[t], red[t+o]);
        __syncthreads();
    }
    double mx = red[0]; __syncthreads();

    double sloc = 0.0;
    for (int j = t; j < N_; j += 256) { double e = exp(lg[j] - mx); lg[j] = e; sloc += e; }
    red[t] = sloc; __syncthreads();
    for (int o = 128; o > 0; o >>= 1) {
        if (t < o) red[t] += red[t+o];
        __syncthreads();
    }
    double Z = red[0];

    for (int j = t; j < N_; j += 256)
        if (j >= 1) phd[((size_t)(b*H_ + h))*1024 + (j-1)] = lg[j] / Z;
}

__global__ __launch_bounds__(256) void topk_kernel(
    const double* __restrict__ phd, float* __restrict__ out)
{
    const int b = blockIdx.x;
    __shared__ double cvals[1024];
    __shared__ double sval[1024];
    __shared__ int    sidx[1024];
    const int t = threadIdx.x;

    for (int i = t; i < 1024; i += 256) {
        double s = 0.0;
        #pragma unroll
        for (int h = 0; h < H_; h++) s += phd[((size_t)(b*H_ + h))*1024 + i];
        s = s / 12.0;
        cvals[i] = s;
        out[OFF_CLS + (size_t)b*1024 + i] = (float)s;
    }

    for (int pass = 0; pass < 2; pass++) {
        const bool desc = (pass == 0);
        __syncthreads();
        for (int i = t; i < 1024; i += 256) { sval[i] = cvals[i]; sidx[i] = i; }
        for (int k = 2; k <= 1024; k <<= 1) {
            for (int j = k >> 1; j > 0; j >>= 1) {
                __syncthreads();
                for (int i = t; i < 1024; i += 256) {
                    int l = i ^ j;
                    if (l > i) {
                        double av = sval[i], bv = sval[l];
                        int    ai = sidx[i], bi = sidx[l];
                        bool before = desc ? (av > bv || (av == bv && ai < bi))
                                           : (av < bv || (av == bv && ai < bi));
                        bool up = ((i & k) == 0);
                        if (up ? !before : before) {
                            sval[i] = bv; sval[l] = av;
                            sidx[i] = bi; sidx[l] = ai;
                        }
                    }
                }
            }
        }
        __syncthreads();
        const size_t idx_off = desc ? (size_t)OFF_EIDX : (size_t)OFF_FIDX;
        const size_t ind_off = desc ? (size_t)OFF_EIND : (size_t)OFF_FIND;
        if (t < 103) out[idx_off + (size_t)b*103 + t] = (float)sidx[t];
        for (int u = t*4; u < 103*768; u += 1024) {
            int e = u / 768;
            float fv = (float)sidx[e];
            *(float4*)&out[ind_off + (size_t)b*103*768 + u] = make_float4(fv, fv, fv, fv);
        }
    }
}

// ---------------------------------------------------------------------------
extern "C" void kernel_launch(void* const* d_in, const int* in_sizes, int n_in,
                              void* d_out, int out_size, void* d_ws, size_t ws_size,
                              hipStream_t stream)
{
    const float* x     = (const float*)d_in[0];
    const float* w_qkv = (const float*)d_in[1];
    const float* w_out = (const float*)d_in[2];
    const float* b_out = (const float*)d_in[3];
    float* out = (float*)d_out;
    float* ws  = (float*)d_ws;

    float*  q    = ws + WS_Q;
    float*  k    = ws + WS_K;
    float*  v    = ws + WS_V;
    float*  ctx  = ws + WS_CTX;
    double* phd  = (double*)(ws + WS_PHD);
    unsigned short* xs   = (unsigned short*)(ws + WS_XS);   // also ctx' later
    unsigned short* qkvB = (unsigned short*)(ws + WS_QKVB);
    unsigned short* outB = (unsigned short*)(ws + WS_OUTB);

    // build split operands
    split_a_kernel<<<(M_PAD*192 + 255)/256, 256, 0, stream>>>(x, xs, M_TOT, M_PAD);
    split_b_kernel<<<(2304*192 + 255)/256, 256, 0, stream>>>(w_qkv, qkvB, 2304);
    split_b_kernel<<<(768*192 + 255)/256, 256, 0, stream>>>(w_out, outB, 768);

    // qkv = x @ w_qkv^T (MFMA split-bf16), scatter to q(0.125x)/k/v
    gemm_qkv_kernel<<<dim3(18, 33), 256, 0, stream>>>(xs, qkvB, q, k, v);

    // attention (fp32) + cls/topk (fp64)
    attn_kernel<<<dim3(17, H_, B_), 256, 0, stream>>>(q, k, v, ctx);
    cls_f64_kernel<<<dim3(H_, B_), 256, 0, stream>>>(x, w_qkv, phd);
    topk_kernel<<<B_, 256, 0, stream>>>(phd, out);

    // out = ctx @ w_out^T + b (MFMA split-bf16); ctx' reuses xs region
    split_a_kernel<<<(M_PAD*192 + 255)/256, 256, 0, stream>>>(ctx, xs, M_TOT, M_PAD);
    gemm_out_kernel<<<dim3(6, 33), 256, 0, stream>>>(xs, outB, b_out, out);
}

// Round 4
// 710.635 us; speedup vs baseline: 1.3314x; 1.1531x over previous
//
#include <hip/hip_runtime.h>

// ---------------------------------------------------------------------------
// SABlock round 4: attention moved to split-bf16 MFMA.
//   S   = Qh.Kh + Qh.Kl + Ql.Kh      (fp32-like accuracy, rel err ~2^-16)
//   ctx = Ph.Vh + Ph.Vl + Pl.Vh
// P round-trips through LDS (C-layout -> A-layout), sharing the K buffer.
// Fully-masked (qtile,ktile) pairs of the CSA block mask are skipped (~15%).
// GEMMs: split-bf16 MFMA (round 3, passing). cls/topk: fp64 (exact indices).
//
// d_out layout (flat f32): out@0, enh_index@3148800, enh_idx@3465216,
//   fuse_index@3465628, fuse_idx@3782044, cls_attn@3782456
// ---------------------------------------------------------------------------

#define B_  4
#define N_  1025
#define C_  768
#define H_  12
#define D_  64
#define M_TOT (B_ * N_)      // 4100
#define M_PAD 4224           // 33 * 128
#define KEXP 2304            // 3 * 768

#define OFF_EIND 3148800
#define OFF_EIDX 3465216
#define OFF_FIND 3465628
#define OFF_FIDX 3782044
#define OFF_CLS  3782456

// workspace offsets (floats)
#define WS_Q     0
#define WS_K     3148800
#define WS_V     6297600
#define WS_CTX   9446400
#define WS_PHD   12595200    // double[4*12*1024]
#define WS_XS    12791808    // ushort[4224*2304]  (A' of x; reused for ctx')
#define WS_QKVB  17657856    // ushort[2304*2304]  (B' of w_qkv)
#define WS_OUTB  20312064    // ushort[768*2304]   (B' of w_out)

typedef short s16x8 __attribute__((ext_vector_type(8)));
typedef float f32x4 __attribute__((ext_vector_type(4)));

__device__ inline unsigned short f2bf(float f) {
    unsigned u = __float_as_uint(f);
    u += 0x7FFF + ((u >> 16) & 1);          // RNE to bf16
    return (unsigned short)(u >> 16);
}
__device__ inline float bf2f(unsigned short h) {
    return __uint_as_float(((unsigned)h) << 16);
}

// ---------------------------------------------------------------------------
// Splitters: fp32 [M x 768] -> ushort bf16 [Mpad x 2304]
// ---------------------------------------------------------------------------
__global__ __launch_bounds__(256) void split_a_kernel(
    const float* __restrict__ src, unsigned short* __restrict__ dst,
    int M, int Mpad)
{
    int idx = blockIdx.x * 256 + threadIdx.x;
    int m = idx / 192, c4 = (idx - m * 192) * 4;
    if (m >= Mpad) return;
    ushort4 hi = make_ushort4(0,0,0,0), lo = hi;
    if (m < M) {
        float4 f = *(const float4*)&src[(size_t)m * C_ + c4];
        hi.x = f2bf(f.x); hi.y = f2bf(f.y); hi.z = f2bf(f.z); hi.w = f2bf(f.w);
        lo.x = f2bf(f.x - bf2f(hi.x)); lo.y = f2bf(f.y - bf2f(hi.y));
        lo.z = f2bf(f.z - bf2f(hi.z)); lo.w = f2bf(f.w - bf2f(hi.w));
    }
    unsigned short* d = dst + (size_t)m * KEXP + c4;
    *(ushort4*)(d)        = hi;
    *(ushort4*)(d + 768)  = hi;
    *(ushort4*)(d + 1536) = lo;
}

__global__ __launch_bounds__(256) void split_b_kernel(
    const float* __restrict__ src, unsigned short* __restrict__ dst, int M)
{
    int idx = blockIdx.x * 256 + threadIdx.x;
    int m = idx / 192, c4 = (idx - m * 192) * 4;
    if (m >= M) return;
    float4 f = *(const float4*)&src[(size_t)m * C_ + c4];
    ushort4 hi, lo;
    hi.x = f2bf(f.x); hi.y = f2bf(f.y); hi.z = f2bf(f.z); hi.w = f2bf(f.w);
    lo.x = f2bf(f.x - bf2f(hi.x)); lo.y = f2bf(f.y - bf2f(hi.y));
    lo.z = f2bf(f.z - bf2f(hi.z)); lo.w = f2bf(f.w - bf2f(hi.w));
    unsigned short* d = dst + (size_t)m * KEXP + c4;
    *(ushort4*)(d)        = hi;
    *(ushort4*)(d + 768)  = lo;
    *(ushort4*)(d + 1536) = hi;
}

// ---------------------------------------------------------------------------
// bf16 MFMA GEMMs (round 3, passing).
// ---------------------------------------------------------------------------
__global__ __launch_bounds__(256) void gemm_qkv_kernel(
    const unsigned short* __restrict__ A, const unsigned short* __restrict__ Bm,
    float* __restrict__ q, float* __restrict__ k, float* __restrict__ v)
{
    __shared__ unsigned short As[128][40];
    __shared__ unsigned short Bs[128][40];
    const int n0 = blockIdx.x * 128;
    const int m0 = blockIdx.y * 128;
    const int t = threadIdx.x;
    const int lane = t & 63, wv = t >> 6;
    const int wr = wv >> 1, wc = wv & 1;
    const int q4 = lane >> 4, r = lane & 15;
    const int srow = t >> 2, scol = (t & 3) * 8;

    f32x4 acc[4][4];
    #pragma unroll
    for (int i = 0; i < 4; i++)
        #pragma unroll
        for (int j = 0; j < 4; j++)
            #pragma unroll
            for (int e = 0; e < 4; e++) acc[i][j][e] = 0.f;

    const unsigned short* a0p = A  + (size_t)(m0 + srow) * KEXP + scol;
    const unsigned short* b0p = Bm + (size_t)(n0 + srow) * KEXP + scol;

    for (int kb = 0; kb < KEXP; kb += 32) {
        uint4 va0 = *(const uint4*)(a0p + kb);
        uint4 va1 = *(const uint4*)(a0p + kb + (size_t)64 * KEXP);
        uint4 vb0 = *(const uint4*)(b0p + kb);
        uint4 vb1 = *(const uint4*)(b0p + kb + (size_t)64 * KEXP);
        __syncthreads();
        *(uint4*)&As[srow][scol]      = va0;
        *(uint4*)&As[srow + 64][scol] = va1;
        *(uint4*)&Bs[srow][scol]      = vb0;
        *(uint4*)&Bs[srow + 64][scol] = vb1;
        __syncthreads();
        s16x8 af[4], bfr[4];
        #pragma unroll
        for (int i = 0; i < 4; i++) {
            af[i]  = *(const s16x8*)&As[wr*64 + i*16 + r][q4*8];
            bfr[i] = *(const s16x8*)&Bs[wc*64 + i*16 + r][q4*8];
        }
        #pragma unroll
        for (int i = 0; i < 4; i++)
            #pragma unroll
            for (int j = 0; j < 4; j++)
                acc[i][j] = __builtin_amdgcn_mfma_f32_16x16x32_bf16(af[i], bfr[j], acc[i][j], 0, 0, 0);
    }

    const int sel = n0 / C_;
    const int off = n0 % C_;
    float* dst = (sel == 0) ? q : (sel == 1) ? k : v;
    const float scl = (sel == 0) ? 0.125f : 1.0f;
    #pragma unroll
    for (int i = 0; i < 4; i++) {
        #pragma unroll
        for (int rr = 0; rr < 4; rr++) {
            int gm = m0 + wr*64 + i*16 + q4*4 + rr;
            if (gm < M_TOT) {
                int bb = gm / N_, n = gm - bb * N_;
                #pragma unroll
                for (int j = 0; j < 4; j++) {
                    int col = off + wc*64 + j*16 + r;
                    int h = col >> 6, d = col & 63;
                    dst[(((size_t)(bb*H_ + h))*N_ + n)*D_ + d] = acc[i][j][rr] * scl;
                }
            }
        }
    }
}

__global__ __launch_bounds__(256) void gemm_out_kernel(
    const unsigned short* __restrict__ A, const unsigned short* __restrict__ Bm,
    const float* __restrict__ bias, float* __restrict__ out)
{
    __shared__ unsigned short As[128][40];
    __shared__ unsigned short Bs[128][40];
    const int n0 = blockIdx.x * 128;
    const int m0 = blockIdx.y * 128;
    const int t = threadIdx.x;
    const int lane = t & 63, wv = t >> 6;
    const int wr = wv >> 1, wc = wv & 1;
    const int q4 = lane >> 4, r = lane & 15;
    const int srow = t >> 2, scol = (t & 3) * 8;

    f32x4 acc[4][4];
    #pragma unroll
    for (int i = 0; i < 4; i++)
        #pragma unroll
        for (int j = 0; j < 4; j++)
            #pragma unroll
            for (int e = 0; e < 4; e++) acc[i][j][e] = 0.f;

    const unsigned short* a0p = A  + (size_t)(m0 + srow) * KEXP + scol;
    const unsigned short* b0p = Bm + (size_t)(n0 + srow) * KEXP + scol;

    for (int kb = 0; kb < KEXP; kb += 32) {
        uint4 va0 = *(const uint4*)(a0p + kb);
        uint4 va1 = *(const uint4*)(a0p + kb + (size_t)64 * KEXP);
        uint4 vb0 = *(const uint4*)(b0p + kb);
        uint4 vb1 = *(const uint4*)(b0p + kb + (size_t)64 * KEXP);
        __syncthreads();
        *(uint4*)&As[srow][scol]      = va0;
        *(uint4*)&As[srow + 64][scol] = va1;
        *(uint4*)&Bs[srow][scol]      = vb0;
        *(uint4*)&Bs[srow + 64][scol] = vb1;
        __syncthreads();
        s16x8 af[4], bfr[4];
        #pragma unroll
        for (int i = 0; i < 4; i++) {
            af[i]  = *(const s16x8*)&As[wr*64 + i*16 + r][q4*8];
            bfr[i] = *(const s16x8*)&Bs[wc*64 + i*16 + r][q4*8];
        }
        #pragma unroll
        for (int i = 0; i < 4; i++)
            #pragma unroll
            for (int j = 0; j < 4; j++)
                acc[i][j] = __builtin_amdgcn_mfma_f32_16x16x32_bf16(af[i], bfr[j], acc[i][j], 0, 0, 0);
    }

    #pragma unroll
    for (int i = 0; i < 4; i++) {
        #pragma unroll
        for (int rr = 0; rr < 4; rr++) {
            int gm = m0 + wr*64 + i*16 + q4*4 + rr;
            if (gm < M_TOT) {
                #pragma unroll
                for (int j = 0; j < 4; j++) {
                    int col = n0 + wc*64 + j*16 + r;
                    out[(size_t)gm * C_ + col] = acc[i][j][rr] + bias[col];
                }
            }
        }
    }
}

// ---------------------------------------------------------------------------
// MFMA flash attention per (qt, h, b). Q-tile 64, K-tile 64, 4 waves: wave w
// owns S/ctx rows w*16..w*16+15. Split-bf16: S = QhKh+QhKl+QlKh,
// ctx += PhVh+PhVl+PlVh. LDS hi|lo stored as two 64-col halves (stride 136).
// KP holds K (phase A) then P (phase B), barrier-separated; P rows are
// written and read by the same wave (no barrier needed after write).
// Fully-masked tiles (CSA diagonal blocks) are skipped block-uniformly.
// ---------------------------------------------------------------------------
__global__ __launch_bounds__(256) void attn_kernel(
    const float* __restrict__ qp, const float* __restrict__ kp,
    const float* __restrict__ vp, float* __restrict__ ctxp)
{
    __shared__ unsigned short Qe[64][136];   // [qrow][Qh 0..63 | Ql 64..127]
    __shared__ unsigned short KP[64][136];   // A: [kvrow][Kh|Kl]; B: [qrow][Ph|Pl]
    __shared__ unsigned short Vt[64][136];   // [d][Vh^T 0..63 | Vl^T 64..127]

    const int qt = blockIdx.x, h = blockIdx.y, b = blockIdx.z;
    const int t = threadIdx.x;
    const int w = t >> 6, lane = t & 63;
    const int quad = lane >> 4, r16 = lane & 15;
    const int q8 = quad * 8;
    const int srow = t >> 2, sseg = (t & 3) * 16;
    const size_t base = ((size_t)(b*H_ + h)) * (N_ * D_);

    // ---- stage Q (fp32 -> bf16 hi/lo) ----
    {
        int n = qt*64 + srow;
        #pragma unroll
        for (int e = 0; e < 4; e++) {
            int d0 = sseg + e*4;
            ushort4 hi = make_ushort4(0,0,0,0), lo = hi;
            if (n < N_) {
                float4 f = *(const float4*)(qp + base + (size_t)n*D_ + d0);
                hi.x = f2bf(f.x); hi.y = f2bf(f.y); hi.z = f2bf(f.z); hi.w = f2bf(f.w);
                lo.x = f2bf(f.x - bf2f(hi.x)); lo.y = f2bf(f.y - bf2f(hi.y));
                lo.z = f2bf(f.z - bf2f(hi.z)); lo.w = f2bf(f.w - bf2f(hi.w));
            }
            *(ushort4*)&Qe[srow][d0]      = hi;
            *(ushort4*)&Qe[srow][64 + d0] = lo;
        }
    }

    // uniform block-id of this Q-tile (-2 = mixed; cls row makes qt=0 mixed)
    int qu;
    {
        int rlo = qt*64, rhi = min(qt*64 + 63, N_ - 1);
        if (rlo == 0) qu = -2;
        else { int b1 = (rlo-1)>>8, b2 = (rhi-1)>>8; qu = (b1==b2) ? b1 : -2; }
    }

    float m_run[4], l_run[4];
    f32x4 ctx[4];
    #pragma unroll
    for (int i = 0; i < 4; i++) {
        m_run[i] = -1e30f; l_run[i] = 0.f;
        #pragma unroll
        for (int e = 0; e < 4; e++) ctx[i][e] = 0.f;
    }

    for (int kt = 0; kt < 17; kt++) {
        // skip fully-masked tile (block-uniform)
        if (qu >= 0 && kt > 0) {
            int clo = kt*64, chi = min(kt*64 + 63, N_ - 1);
            int b1 = (clo-1)>>8, b2 = (chi-1)>>8;
            if (b1 == b2 && b1 == qu) continue;
        }

        __syncthreads();   // previous iter's KP/Vt readers done
        {   // ---- stage K (hi|lo) and V^T (hi|lo) ----
            int n = kt*64 + srow;
            #pragma unroll
            for (int e = 0; e < 4; e++) {
                int d0 = sseg + e*4;
                ushort4 khi = make_ushort4(0,0,0,0), klo = khi;
                ushort4 vhi = khi, vlo = khi;
                if (n < N_) {
                    float4 f = *(const float4*)(kp + base + (size_t)n*D_ + d0);
                    khi.x = f2bf(f.x); khi.y = f2bf(f.y); khi.z = f2bf(f.z); khi.w = f2bf(f.w);
                    klo.x = f2bf(f.x - bf2f(khi.x)); klo.y = f2bf(f.y - bf2f(khi.y));
                    klo.z = f2bf(f.z - bf2f(khi.z)); klo.w = f2bf(f.w - bf2f(khi.w));
                    float4 g = *(const float4*)(vp + base + (size_t)n*D_ + d0);
                    vhi.x = f2bf(g.x); vhi.y = f2bf(g.y); vhi.z = f2bf(g.z); vhi.w = f2bf(g.w);
                    vlo.x = f2bf(g.x - bf2f(vhi.x)); vlo.y = f2bf(g.y - bf2f(vhi.y));
                    vlo.z = f2bf(g.z - bf2f(vhi.z)); vlo.w = f2bf(g.w - bf2f(vhi.w));
                }
                *(ushort4*)&KP[srow][d0]      = khi;
                *(ushort4*)&KP[srow][64 + d0] = klo;
                Vt[d0+0][srow] = vhi.x; Vt[d0+1][srow] = vhi.y;
                Vt[d0+2][srow] = vhi.z; Vt[d0+3][srow] = vhi.w;
                Vt[d0+0][64+srow] = vlo.x; Vt[d0+1][64+srow] = vlo.y;
                Vt[d0+2][64+srow] = vlo.z; Vt[d0+3][64+srow] = vlo.w;
            }
        }
        __syncthreads();

        // ---- S = Q K^T (split-bf16 MFMA) ----
        f32x4 st[4];
        #pragma unroll
        for (int j = 0; j < 4; j++)
            #pragma unroll
            for (int e = 0; e < 4; e++) st[j][e] = 0.f;
        {
            const int ar = w*16 + r16;
            s16x8 ah0 = *(const s16x8*)&Qe[ar][q8];
            s16x8 ah1 = *(const s16x8*)&Qe[ar][32 + q8];
            s16x8 al0 = *(const s16x8*)&Qe[ar][64 + q8];
            s16x8 al1 = *(const s16x8*)&Qe[ar][96 + q8];
            #pragma unroll
            for (int j = 0; j < 4; j++) {
                const int br = j*16 + r16;
                s16x8 bh0 = *(const s16x8*)&KP[br][q8];
                s16x8 bh1 = *(const s16x8*)&KP[br][32 + q8];
                s16x8 bl0 = *(const s16x8*)&KP[br][64 + q8];
                s16x8 bl1 = *(const s16x8*)&KP[br][96 + q8];
                st[j] = __builtin_amdgcn_mfma_f32_16x16x32_bf16(ah0, bh0, st[j], 0,0,0);
                st[j] = __builtin_amdgcn_mfma_f32_16x16x32_bf16(ah1, bh1, st[j], 0,0,0);
                st[j] = __builtin_amdgcn_mfma_f32_16x16x32_bf16(ah0, bl0, st[j], 0,0,0);
                st[j] = __builtin_amdgcn_mfma_f32_16x16x32_bf16(ah1, bl1, st[j], 0,0,0);
                st[j] = __builtin_amdgcn_mfma_f32_16x16x32_bf16(al0, bh0, st[j], 0,0,0);
                st[j] = __builtin_amdgcn_mfma_f32_16x16x32_bf16(al1, bh1, st[j], 0,0,0);
            }
        }

        // ---- mask + online softmax (C/D layout: row=quad*4+reg, col=j*16+r16)
        float pv[4][4];     // p values [reg][j]
        float alpha[4];
        #pragma unroll
        for (int reg = 0; reg < 4; reg++) {
            int gr = qt*64 + w*16 + quad*4 + reg;
            int qb = (gr >= 1) ? ((gr - 1) >> 8) : -1;
            float mx = -1e30f;
            float vv[4];
            #pragma unroll
            for (int j = 0; j < 4; j++) {
                int gc = kt*64 + j*16 + r16;
                bool ok = (gr < N_) && (gc < N_) &&
                          !((gr >= 1) && (gc >= 1) && (((gc - 1) >> 8) == qb));
                vv[j] = ok ? st[j][reg] : -1e30f;
                mx = fmaxf(mx, vv[j]);
            }
            mx = fmaxf(mx, __shfl_xor(mx, 1));
            mx = fmaxf(mx, __shfl_xor(mx, 2));
            mx = fmaxf(mx, __shfl_xor(mx, 4));
            mx = fmaxf(mx, __shfl_xor(mx, 8));
            float mnew = fmaxf(m_run[reg], mx);
            alpha[reg] = __expf(m_run[reg] - mnew);
            m_run[reg] = mnew;
            float ps = 0.f;
            #pragma unroll
            for (int j = 0; j < 4; j++) {
                float p = (vv[j] > -1e29f) ? __expf(vv[j] - mnew) : 0.f;
                pv[reg][j] = p; ps += p;
            }
            ps += __shfl_xor(ps, 1);
            ps += __shfl_xor(ps, 2);
            ps += __shfl_xor(ps, 4);
            ps += __shfl_xor(ps, 8);
            l_run[reg] = l_run[reg] * alpha[reg] + ps;
        }

        __syncthreads();   // all waves done reading K from KP

        // write P (hi|lo) into KP rows of this wave
        #pragma unroll
        for (int reg = 0; reg < 4; reg++) {
            int lrow = w*16 + quad*4 + reg;
            #pragma unroll
            for (int j = 0; j < 4; j++) {
                float p = pv[reg][j];
                unsigned short ph = f2bf(p);
                unsigned short pl = f2bf(p - bf2f(ph));
                KP[lrow][j*16 + r16]      = ph;
                KP[lrow][64 + j*16 + r16] = pl;
            }
        }

        // rescale ctx by alpha (row = quad*4+reg matches acc reg index)
        #pragma unroll
        for (int nj = 0; nj < 4; nj++)
            #pragma unroll
            for (int reg = 0; reg < 4; reg++)
                ctx[nj][reg] *= alpha[reg];

        // ---- ctx += P V (split-bf16 MFMA); P rows self-written, no barrier
        {
            const int ar = w*16 + r16;
            s16x8 ph0 = *(const s16x8*)&KP[ar][q8];
            s16x8 ph1 = *(const s16x8*)&KP[ar][32 + q8];
            s16x8 pl0 = *(const s16x8*)&KP[ar][64 + q8];
            s16x8 pl1 = *(const s16x8*)&KP[ar][96 + q8];
            #pragma unroll
            for (int nj = 0; nj < 4; nj++) {
                const int br = nj*16 + r16;
                s16x8 vh0 = *(const s16x8*)&Vt[br][q8];
                s16x8 vh1 = *(const s16x8*)&Vt[br][32 + q8];
                s16x8 vl0 = *(const s16x8*)&Vt[br][64 + q8];
                s16x8 vl1 = *(const s16x8*)&Vt[br][96 + q8];
                ctx[nj] = __builtin_amdgcn_mfma_f32_16x16x32_bf16(ph0, vh0, ctx[nj], 0,0,0);
                ctx[nj] = __builtin_amdgcn_mfma_f32_16x16x32_bf16(ph1, vh1, ctx[nj], 0,0,0);
                ctx[nj] = __builtin_amdgcn_mfma_f32_16x16x32_bf16(ph0, vl0, ctx[nj], 0,0,0);
                ctx[nj] = __builtin_amdgcn_mfma_f32_16x16x32_bf16(ph1, vl1, ctx[nj], 0,0,0);
                ctx[nj] = __builtin_amdgcn_mfma_f32_16x16x32_bf16(pl0, vh0, ctx[nj], 0,0,0);
                ctx[nj] = __builtin_amdgcn_mfma_f32_16x16x32_bf16(pl1, vh1, ctx[nj], 0,0,0);
            }
        }
    }

    // ---- epilogue: ctx / l -> ctxp[b][n][h*64 + d]
    #pragma unroll
    for (int reg = 0; reg < 4; reg++) {
        int gr = qt*64 + w*16 + quad*4 + reg;
        if (gr < N_) {
            float inv = 1.0f / l_run[reg];
            #pragma unroll
            for (int nj = 0; nj < 4; nj++)
                ctxp[((size_t)(b*N_ + gr))*C_ + h*64 + nj*16 + r16] = ctx[nj][reg] * inv;
        }
    }
}

// ---------------------------------------------------------------------------
// cls path fp64 + topk (unchanged, passing).
// ---------------------------------------------------------------------------
__global__ __launch_bounds__(256) void cls_f64_kernel(
    const float* __restrict__ x, const float* __restrict__ w_qkv,
    double* __restrict__ phd)
{
    const int h = blockIdx.x, b = blockIdx.y;
    __shared__ float  x0s[768];
    __shared__ double q0s[64];
    __shared__ double ms[768];
    __shared__ double lg[1025];
    __shared__ double red[256];
    const int t = threadIdx.x;
    const float* xb = x + (size_t)b * N_ * C_;

    for (int c = t; c < C_; c += 256) x0s[c] = xb[c];
    __syncthreads();

    if (t < 64) {
        const float* wr = w_qkv + (size_t)(h*64 + t) * C_;
        double s = 0.0;
        for (int c = 0; c < C_; c++) s += (double)x0s[c] * (double)wr[c];
        q0s[t] = s * 0.125;
    }
    __syncthreads();

    for (int c = t; c < C_; c += 256) {
        const float* wk = w_qkv + (size_t)(C_ + h*64) * C_ + c;
        double s = 0.0;
        #pragma unroll 8
        for (int d = 0; d < 64; d++) s += q0s[d] * (double)wk[(size_t)d * C_];
        ms[c] = s;
    }
    __syncthreads();

    for (int j = t; j < N_; j += 256) {
        const float* xr = xb + (size_t)j * C_;
        double s = 0.0;
        #pragma unroll 4
        for (int c = 0; c < C_; c++) s += (double)xr[c] * ms[c];
        lg[j] = s;
    }
    __syncthreads();

    double mloc = -1e300;
    for (int j = t; j < N_; j += 256) mloc = fmax(mloc, lg[j]);
    red[t] = mloc; __syncthreads();
    for (int o = 128; o > 0; o >>= 1) {
        if (t < o) red[t] = fmax(red[t], red[t+o]);
        __syncthreads();
    }
    double mx = red[0]; __syncthreads();

    double sloc = 0.0;
    for (int j = t; j < N_; j += 256) { double e = exp(lg[j] - mx); lg[j] = e; sloc += e; }
    red[t] = sloc; __syncthreads();
    for (int o = 128; o > 0; o >>= 1) {
        if (t < o) red[t] += red[t+o];
        __syncthreads();
    }
    double Z = red[0];

    for (int j = t; j < N_; j += 256)
        if (j >= 1) phd[((size_t)(b*H_ + h))*1024 + (j-1)] = lg[j] / Z;
}

__global__ __launch_bounds__(256) void topk_kernel(
    const double* __restrict__ phd, float* __restrict__ out)
{
    const int b = blockIdx.x;
    __shared__ double cvals[1024];
    __shared__ double sval[1024];
    __shared__ int    sidx[1024];
    const int t = threadIdx.x;

    for (int i = t; i < 1024; i += 256) {
        double s = 0.0;
        #pragma unroll
        for (int h = 0; h < H_; h++) s += phd[((size_t)(b*H_ + h))*1024 + i];
        s = s / 12.0;
        cvals[i] = s;
        out[OFF_CLS + (size_t)b*1024 + i] = (float)s;
    }

    for (int pass = 0; pass < 2; pass++) {
        const bool desc = (pass == 0);
        __syncthreads();
        for (int i = t; i < 1024; i += 256) { sval[i] = cvals[i]; sidx[i] = i; }
        for (int k = 2; k <= 1024; k <<= 1) {
            for (int j = k >> 1; j > 0; j >>= 1) {
                __syncthreads();
                for (int i = t; i < 1024; i += 256) {
                    int l = i ^ j;
                    if (l > i) {
                        double av = sval[i], bv = sval[l];
                        int    ai = sidx[i], bi = sidx[l];
                        bool before = desc ? (av > bv || (av == bv && ai < bi))
                                           : (av < bv || (av == bv && ai < bi));
                        bool up = ((i & k) == 0);
                        if (up ? !before : before) {
                            sval[i] = bv; sval[l] = av;
                            sidx[i] = bi; sidx[l] = ai;
                        }
                    }
                }
            }
        }
        __syncthreads();
        const size_t idx_off = desc ? (size_t)OFF_EIDX : (size_t)OFF_FIDX;
        const size_t ind_off = desc ? (size_t)OFF_EIND : (size_t)OFF_FIND;
        if (t < 103) out[idx_off + (size_t)b*103 + t] = (float)sidx[t];
        for (int u = t*4; u < 103*768; u += 1024) {
            int e = u / 768;
            float fv = (float)sidx[e];
            *(float4*)&out[ind_off + (size_t)b*103*768 + u] = make_float4(fv, fv, fv, fv);
        }
    }
}

// ---------------------------------------------------------------------------
extern "C" void kernel_launch(void* const* d_in, const int* in_sizes, int n_in,
                              void* d_out, int out_size, void* d_ws, size_t ws_size,
                              hipStream_t stream)
{
    const float* x     = (const float*)d_in[0];
    const float* w_qkv = (const float*)d_in[1];
    const float* w_out = (const float*)d_in[2];
    const float* b_out = (const float*)d_in[3];
    float* out = (float*)d_out;
    float* ws  = (float*)d_ws;

    float*  q    = ws + WS_Q;
    float*  k    = ws + WS_K;
    float*  v    = ws + WS_V;
    float*  ctx  = ws + WS_CTX;
    double* phd  = (double*)(ws + WS_PHD);
    unsigned short* xs   = (unsigned short*)(ws + WS_XS);
    unsigned short* qkvB = (unsigned short*)(ws + WS_QKVB);
    unsigned short* outB = (unsigned short*)(ws + WS_OUTB);

    split_a_kernel<<<(M_PAD*192 + 255)/256, 256, 0, stream>>>(x, xs, M_TOT, M_PAD);
    split_b_kernel<<<(2304*192 + 255)/256, 256, 0, stream>>>(w_qkv, qkvB, 2304);
    split_b_kernel<<<(768*192 + 255)/256, 256, 0, stream>>>(w_out, outB, 768);

    gemm_qkv_kernel<<<dim3(18, 33), 256, 0, stream>>>(xs, qkvB, q, k, v);

    attn_kernel<<<dim3(17, H_, B_), 256, 0, stream>>>(q, k, v, ctx);
    cls_f64_kernel<<<dim3(H_, B_), 256, 0, stream>>>(x, w_qkv, phd);
    topk_kernel<<<B_, 256, 0, stream>>>(phd, out);

    split_a_kernel<<<(M_PAD*192 + 255)/256, 256, 0, stream>>>(ctx, xs, M_TOT, M_PAD);
    gemm_out_kernel<<<dim3(6, 33), 256, 0, stream>>>(xs, outB, b_out, out);
}

// Round 5
// 589.914 us; speedup vs baseline: 1.6039x; 1.2046x over previous
//
#include <hip/hip_runtime.h>

// ---------------------------------------------------------------------------
// SABlock round 5: cls fp64 path re-sharded for occupancy (was 48 blocks,
// VALUBusy 1.5%, 195 us). Same fp64 math -> same ordering, ~30 us.
// GEMMs + attention: split-bf16 MFMA (rounds 3/4, passing).
//
// d_out layout (flat f32): out@0, enh_index@3148800, enh_idx@3465216,
//   fuse_index@3465628, fuse_idx@3782044, cls_attn@3782456
// ---------------------------------------------------------------------------

#define B_  4
#define N_  1025
#define C_  768
#define H_  12
#define D_  64
#define M_TOT (B_ * N_)      // 4100
#define M_PAD 4224           // 33 * 128
#define KEXP 2304            // 3 * 768

#define OFF_EIND 3148800
#define OFF_EIDX 3465216
#define OFF_FIND 3465628
#define OFF_FIDX 3782044
#define OFF_CLS  3782456

// workspace offsets (floats)
#define WS_Q     0
#define WS_K     3148800
#define WS_V     6297600
#define WS_CTX   9446400
#define WS_F64   12595200    // double region (196608 floats = 98304 doubles)
#define WS_XS    12791808    // ushort[4224*2304]  (A' of x; reused for ctx')
#define WS_QKVB  17657856    // ushort[2304*2304]  (B' of w_qkv)
#define WS_OUTB  20312064    // ushort[768*2304]   (B' of w_out)

// double-region layout (indices into double*)
#define DQ0 0                // [4*12*64]   = 3072
#define DMS 3072             // [4*12*768]  = 36864
#define DLG 39936            // [4*12*1025] = 49200  (total 89136 < 98304)

typedef short s16x8 __attribute__((ext_vector_type(8)));
typedef float f32x4 __attribute__((ext_vector_type(4)));

__device__ inline unsigned short f2bf(float f) {
    unsigned u = __float_as_uint(f);
    u += 0x7FFF + ((u >> 16) & 1);          // RNE to bf16
    return (unsigned short)(u >> 16);
}
__device__ inline float bf2f(unsigned short h) {
    return __uint_as_float(((unsigned)h) << 16);
}

// ---------------------------------------------------------------------------
// Splitters: fp32 [M x 768] -> ushort bf16 [Mpad x 2304]
// ---------------------------------------------------------------------------
__global__ __launch_bounds__(256) void split_a_kernel(
    const float* __restrict__ src, unsigned short* __restrict__ dst,
    int M, int Mpad)
{
    int idx = blockIdx.x * 256 + threadIdx.x;
    int m = idx / 192, c4 = (idx - m * 192) * 4;
    if (m >= Mpad) return;
    ushort4 hi = make_ushort4(0,0,0,0), lo = hi;
    if (m < M) {
        float4 f = *(const float4*)&src[(size_t)m * C_ + c4];
        hi.x = f2bf(f.x); hi.y = f2bf(f.y); hi.z = f2bf(f.z); hi.w = f2bf(f.w);
        lo.x = f2bf(f.x - bf2f(hi.x)); lo.y = f2bf(f.y - bf2f(hi.y));
        lo.z = f2bf(f.z - bf2f(hi.z)); lo.w = f2bf(f.w - bf2f(hi.w));
    }
    unsigned short* d = dst + (size_t)m * KEXP + c4;
    *(ushort4*)(d)        = hi;
    *(ushort4*)(d + 768)  = hi;
    *(ushort4*)(d + 1536) = lo;
}

__global__ __launch_bounds__(256) void split_b_kernel(
    const float* __restrict__ src, unsigned short* __restrict__ dst, int M)
{
    int idx = blockIdx.x * 256 + threadIdx.x;
    int m = idx / 192, c4 = (idx - m * 192) * 4;
    if (m >= M) return;
    float4 f = *(const float4*)&src[(size_t)m * C_ + c4];
    ushort4 hi, lo;
    hi.x = f2bf(f.x); hi.y = f2bf(f.y); hi.z = f2bf(f.z); hi.w = f2bf(f.w);
    lo.x = f2bf(f.x - bf2f(hi.x)); lo.y = f2bf(f.y - bf2f(hi.y));
    lo.z = f2bf(f.z - bf2f(hi.z)); lo.w = f2bf(f.w - bf2f(hi.w));
    unsigned short* d = dst + (size_t)m * KEXP + c4;
    *(ushort4*)(d)        = hi;
    *(ushort4*)(d + 768)  = lo;
    *(ushort4*)(d + 1536) = hi;
}

// ---------------------------------------------------------------------------
// bf16 MFMA GEMMs (round 3, passing).
// ---------------------------------------------------------------------------
__global__ __launch_bounds__(256) void gemm_qkv_kernel(
    const unsigned short* __restrict__ A, const unsigned short* __restrict__ Bm,
    float* __restrict__ q, float* __restrict__ k, float* __restrict__ v)
{
    __shared__ unsigned short As[128][40];
    __shared__ unsigned short Bs[128][40];
    const int n0 = blockIdx.x * 128;
    const int m0 = blockIdx.y * 128;
    const int t = threadIdx.x;
    const int lane = t & 63, wv = t >> 6;
    const int wr = wv >> 1, wc = wv & 1;
    const int q4 = lane >> 4, r = lane & 15;
    const int srow = t >> 2, scol = (t & 3) * 8;

    f32x4 acc[4][4];
    #pragma unroll
    for (int i = 0; i < 4; i++)
        #pragma unroll
        for (int j = 0; j < 4; j++)
            #pragma unroll
            for (int e = 0; e < 4; e++) acc[i][j][e] = 0.f;

    const unsigned short* a0p = A  + (size_t)(m0 + srow) * KEXP + scol;
    const unsigned short* b0p = Bm + (size_t)(n0 + srow) * KEXP + scol;

    for (int kb = 0; kb < KEXP; kb += 32) {
        uint4 va0 = *(const uint4*)(a0p + kb);
        uint4 va1 = *(const uint4*)(a0p + kb + (size_t)64 * KEXP);
        uint4 vb0 = *(const uint4*)(b0p + kb);
        uint4 vb1 = *(const uint4*)(b0p + kb + (size_t)64 * KEXP);
        __syncthreads();
        *(uint4*)&As[srow][scol]      = va0;
        *(uint4*)&As[srow + 64][scol] = va1;
        *(uint4*)&Bs[srow][scol]      = vb0;
        *(uint4*)&Bs[srow + 64][scol] = vb1;
        __syncthreads();
        s16x8 af[4], bfr[4];
        #pragma unroll
        for (int i = 0; i < 4; i++) {
            af[i]  = *(const s16x8*)&As[wr*64 + i*16 + r][q4*8];
            bfr[i] = *(const s16x8*)&Bs[wc*64 + i*16 + r][q4*8];
        }
        #pragma unroll
        for (int i = 0; i < 4; i++)
            #pragma unroll
            for (int j = 0; j < 4; j++)
                acc[i][j] = __builtin_amdgcn_mfma_f32_16x16x32_bf16(af[i], bfr[j], acc[i][j], 0, 0, 0);
    }

    const int sel = n0 / C_;
    const int off = n0 % C_;
    float* dst = (sel == 0) ? q : (sel == 1) ? k : v;
    const float scl = (sel == 0) ? 0.125f : 1.0f;
    #pragma unroll
    for (int i = 0; i < 4; i++) {
        #pragma unroll
        for (int rr = 0; rr < 4; rr++) {
            int gm = m0 + wr*64 + i*16 + q4*4 + rr;
            if (gm < M_TOT) {
                int bb = gm / N_, n = gm - bb * N_;
                #pragma unroll
                for (int j = 0; j < 4; j++) {
                    int col = off + wc*64 + j*16 + r;
                    int h = col >> 6, d = col & 63;
                    dst[(((size_t)(bb*H_ + h))*N_ + n)*D_ + d] = acc[i][j][rr] * scl;
                }
            }
        }
    }
}

__global__ __launch_bounds__(256) void gemm_out_kernel(
    const unsigned short* __restrict__ A, const unsigned short* __restrict__ Bm,
    const float* __restrict__ bias, float* __restrict__ out)
{
    __shared__ unsigned short As[128][40];
    __shared__ unsigned short Bs[128][40];
    const int n0 = blockIdx.x * 128;
    const int m0 = blockIdx.y * 128;
    const int t = threadIdx.x;
    const int lane = t & 63, wv = t >> 6;
    const int wr = wv >> 1, wc = wv & 1;
    const int q4 = lane >> 4, r = lane & 15;
    const int srow = t >> 2, scol = (t & 3) * 8;

    f32x4 acc[4][4];
    #pragma unroll
    for (int i = 0; i < 4; i++)
        #pragma unroll
        for (int j = 0; j < 4; j++)
            #pragma unroll
            for (int e = 0; e < 4; e++) acc[i][j][e] = 0.f;

    const unsigned short* a0p = A  + (size_t)(m0 + srow) * KEXP + scol;
    const unsigned short* b0p = Bm + (size_t)(n0 + srow) * KEXP + scol;

    for (int kb = 0; kb < KEXP; kb += 32) {
        uint4 va0 = *(const uint4*)(a0p + kb);
        uint4 va1 = *(const uint4*)(a0p + kb + (size_t)64 * KEXP);
        uint4 vb0 = *(const uint4*)(b0p + kb);
        uint4 vb1 = *(const uint4*)(b0p + kb + (size_t)64 * KEXP);
        __syncthreads();
        *(uint4*)&As[srow][scol]      = va0;
        *(uint4*)&As[srow + 64][scol] = va1;
        *(uint4*)&Bs[srow][scol]      = vb0;
        *(uint4*)&Bs[srow + 64][scol] = vb1;
        __syncthreads();
        s16x8 af[4], bfr[4];
        #pragma unroll
        for (int i = 0; i < 4; i++) {
            af[i]  = *(const s16x8*)&As[wr*64 + i*16 + r][q4*8];
            bfr[i] = *(const s16x8*)&Bs[wc*64 + i*16 + r][q4*8];
        }
        #pragma unroll
        for (int i = 0; i < 4; i++)
            #pragma unroll
            for (int j = 0; j < 4; j++)
                acc[i][j] = __builtin_amdgcn_mfma_f32_16x16x32_bf16(af[i], bfr[j], acc[i][j], 0, 0, 0);
    }

    #pragma unroll
    for (int i = 0; i < 4; i++) {
        #pragma unroll
        for (int rr = 0; rr < 4; rr++) {
            int gm = m0 + wr*64 + i*16 + q4*4 + rr;
            if (gm < M_TOT) {
                #pragma unroll
                for (int j = 0; j < 4; j++) {
                    int col = n0 + wc*64 + j*16 + r;
                    out[(size_t)gm * C_ + col] = acc[i][j][rr] + bias[col];
                }
            }
        }
    }
}

// ---------------------------------------------------------------------------
// MFMA flash attention (round 4, passing).
// ---------------------------------------------------------------------------
__global__ __launch_bounds__(256) void attn_kernel(
    const float* __restrict__ qp, const float* __restrict__ kp,
    const float* __restrict__ vp, float* __restrict__ ctxp)
{
    __shared__ unsigned short Qe[64][136];
    __shared__ unsigned short KP[64][136];
    __shared__ unsigned short Vt[64][136];

    const int qt = blockIdx.x, h = blockIdx.y, b = blockIdx.z;
    const int t = threadIdx.x;
    const int w = t >> 6, lane = t & 63;
    const int quad = lane >> 4, r16 = lane & 15;
    const int q8 = quad * 8;
    const int srow = t >> 2, sseg = (t & 3) * 16;
    const size_t base = ((size_t)(b*H_ + h)) * (N_ * D_);

    {
        int n = qt*64 + srow;
        #pragma unroll
        for (int e = 0; e < 4; e++) {
            int d0 = sseg + e*4;
            ushort4 hi = make_ushort4(0,0,0,0), lo = hi;
            if (n < N_) {
                float4 f = *(const float4*)(qp + base + (size_t)n*D_ + d0);
                hi.x = f2bf(f.x); hi.y = f2bf(f.y); hi.z = f2bf(f.z); hi.w = f2bf(f.w);
                lo.x = f2bf(f.x - bf2f(hi.x)); lo.y = f2bf(f.y - bf2f(hi.y));
                lo.z = f2bf(f.z - bf2f(hi.z)); lo.w = f2bf(f.w - bf2f(hi.w));
            }
            *(ushort4*)&Qe[srow][d0]      = hi;
            *(ushort4*)&Qe[srow][64 + d0] = lo;
        }
    }

    int qu;
    {
        int rlo = qt*64, rhi = min(qt*64 + 63, N_ - 1);
        if (rlo == 0) qu = -2;
        else { int b1 = (rlo-1)>>8, b2 = (rhi-1)>>8; qu = (b1==b2) ? b1 : -2; }
    }

    float m_run[4], l_run[4];
    f32x4 ctx[4];
    #pragma unroll
    for (int i = 0; i < 4; i++) {
        m_run[i] = -1e30f; l_run[i] = 0.f;
        #pragma unroll
        for (int e = 0; e < 4; e++) ctx[i][e] = 0.f;
    }

    for (int kt = 0; kt < 17; kt++) {
        if (qu >= 0 && kt > 0) {
            int clo = kt*64, chi = min(kt*64 + 63, N_ - 1);
            int b1 = (clo-1)>>8, b2 = (chi-1)>>8;
            if (b1 == b2 && b1 == qu) continue;
        }

        __syncthreads();
        {
            int n = kt*64 + srow;
            #pragma unroll
            for (int e = 0; e < 4; e++) {
                int d0 = sseg + e*4;
                ushort4 khi = make_ushort4(0,0,0,0), klo = khi;
                ushort4 vhi = khi, vlo = khi;
                if (n < N_) {
                    float4 f = *(const float4*)(kp + base + (size_t)n*D_ + d0);
                    khi.x = f2bf(f.x); khi.y = f2bf(f.y); khi.z = f2bf(f.z); khi.w = f2bf(f.w);
                    klo.x = f2bf(f.x - bf2f(khi.x)); klo.y = f2bf(f.y - bf2f(khi.y));
                    klo.z = f2bf(f.z - bf2f(khi.z)); klo.w = f2bf(f.w - bf2f(khi.w));
                    float4 g = *(const float4*)(vp + base + (size_t)n*D_ + d0);
                    vhi.x = f2bf(g.x); vhi.y = f2bf(g.y); vhi.z = f2bf(g.z); vhi.w = f2bf(g.w);
                    vlo.x = f2bf(g.x - bf2f(vhi.x)); vlo.y = f2bf(g.y - bf2f(vhi.y));
                    vlo.z = f2bf(g.z - bf2f(vhi.z)); vlo.w = f2bf(g.w - bf2f(vhi.w));
                }
                *(ushort4*)&KP[srow][d0]      = khi;
                *(ushort4*)&KP[srow][64 + d0] = klo;
                Vt[d0+0][srow] = vhi.x; Vt[d0+1][srow] = vhi.y;
                Vt[d0+2][srow] = vhi.z; Vt[d0+3][srow] = vhi.w;
                Vt[d0+0][64+srow] = vlo.x; Vt[d0+1][64+srow] = vlo.y;
                Vt[d0+2][64+srow] = vlo.z; Vt[d0+3][64+srow] = vlo.w;
            }
        }
        __syncthreads();

        f32x4 st[4];
        #pragma unroll
        for (int j = 0; j < 4; j++)
            #pragma unroll
            for (int e = 0; e < 4; e++) st[j][e] = 0.f;
        {
            const int ar = w*16 + r16;
            s16x8 ah0 = *(const s16x8*)&Qe[ar][q8];
            s16x8 ah1 = *(const s16x8*)&Qe[ar][32 + q8];
            s16x8 al0 = *(const s16x8*)&Qe[ar][64 + q8];
            s16x8 al1 = *(const s16x8*)&Qe[ar][96 + q8];
            #pragma unroll
            for (int j = 0; j < 4; j++) {
                const int br = j*16 + r16;
                s16x8 bh0 = *(const s16x8*)&KP[br][q8];
                s16x8 bh1 = *(const s16x8*)&KP[br][32 + q8];
                s16x8 bl0 = *(const s16x8*)&KP[br][64 + q8];
                s16x8 bl1 = *(const s16x8*)&KP[br][96 + q8];
                st[j] = __builtin_amdgcn_mfma_f32_16x16x32_bf16(ah0, bh0, st[j], 0,0,0);
                st[j] = __builtin_amdgcn_mfma_f32_16x16x32_bf16(ah1, bh1, st[j], 0,0,0);
                st[j] = __builtin_amdgcn_mfma_f32_16x16x32_bf16(ah0, bl0, st[j], 0,0,0);
                st[j] = __builtin_amdgcn_mfma_f32_16x16x32_bf16(ah1, bl1, st[j], 0,0,0);
                st[j] = __builtin_amdgcn_mfma_f32_16x16x32_bf16(al0, bh0, st[j], 0,0,0);
                st[j] = __builtin_amdgcn_mfma_f32_16x16x32_bf16(al1, bh1, st[j], 0,0,0);
            }
        }

        float pv[4][4];
        float alpha[4];
        #pragma unroll
        for (int reg = 0; reg < 4; reg++) {
            int gr = qt*64 + w*16 + quad*4 + reg;
            int qb = (gr >= 1) ? ((gr - 1) >> 8) : -1;
            float mx = -1e30f;
            float vv[4];
            #pragma unroll
            for (int j = 0; j < 4; j++) {
                int gc = kt*64 + j*16 + r16;
                bool ok = (gr < N_) && (gc < N_) &&
                          !((gr >= 1) && (gc >= 1) && (((gc - 1) >> 8) == qb));
                vv[j] = ok ? st[j][reg] : -1e30f;
                mx = fmaxf(mx, vv[j]);
            }
            mx = fmaxf(mx, __shfl_xor(mx, 1));
            mx = fmaxf(mx, __shfl_xor(mx, 2));
            mx = fmaxf(mx, __shfl_xor(mx, 4));
            mx = fmaxf(mx, __shfl_xor(mx, 8));
            float mnew = fmaxf(m_run[reg], mx);
            alpha[reg] = __expf(m_run[reg] - mnew);
            m_run[reg] = mnew;
            float ps = 0.f;
            #pragma unroll
            for (int j = 0; j < 4; j++) {
                float p = (vv[j] > -1e29f) ? __expf(vv[j] - mnew) : 0.f;
                pv[reg][j] = p; ps += p;
            }
            ps += __shfl_xor(ps, 1);
            ps += __shfl_xor(ps, 2);
            ps += __shfl_xor(ps, 4);
            ps += __shfl_xor(ps, 8);
            l_run[reg] = l_run[reg] * alpha[reg] + ps;
        }

        __syncthreads();

        #pragma unroll
        for (int reg = 0; reg < 4; reg++) {
            int lrow = w*16 + quad*4 + reg;
            #pragma unroll
            for (int j = 0; j < 4; j++) {
                float p = pv[reg][j];
                unsigned short ph = f2bf(p);
                unsigned short pl = f2bf(p - bf2f(ph));
                KP[lrow][j*16 + r16]      = ph;
                KP[lrow][64 + j*16 + r16] = pl;
            }
        }

        #pragma unroll
        for (int nj = 0; nj < 4; nj++)
            #pragma unroll
            for (int reg = 0; reg < 4; reg++)
                ctx[nj][reg] *= alpha[reg];

        {
            const int ar = w*16 + r16;
            s16x8 ph0 = *(const s16x8*)&KP[ar][q8];
            s16x8 ph1 = *(const s16x8*)&KP[ar][32 + q8];
            s16x8 pl0 = *(const s16x8*)&KP[ar][64 + q8];
            s16x8 pl1 = *(const s16x8*)&KP[ar][96 + q8];
            #pragma unroll
            for (int nj = 0; nj < 4; nj++) {
                const int br = nj*16 + r16;
                s16x8 vh0 = *(const s16x8*)&Vt[br][q8];
                s16x8 vh1 = *(const s16x8*)&Vt[br][32 + q8];
                s16x8 vl0 = *(const s16x8*)&Vt[br][64 + q8];
                s16x8 vl1 = *(const s16x8*)&Vt[br][96 + q8];
                ctx[nj] = __builtin_amdgcn_mfma_f32_16x16x32_bf16(ph0, vh0, ctx[nj], 0,0,0);
                ctx[nj] = __builtin_amdgcn_mfma_f32_16x16x32_bf16(ph1, vh1, ctx[nj], 0,0,0);
                ctx[nj] = __builtin_amdgcn_mfma_f32_16x16x32_bf16(ph0, vl0, ctx[nj], 0,0,0);
                ctx[nj] = __builtin_amdgcn_mfma_f32_16x16x32_bf16(ph1, vl1, ctx[nj], 0,0,0);
                ctx[nj] = __builtin_amdgcn_mfma_f32_16x16x32_bf16(pl0, vh0, ctx[nj], 0,0,0);
                ctx[nj] = __builtin_amdgcn_mfma_f32_16x16x32_bf16(pl1, vh1, ctx[nj], 0,0,0);
            }
        }
    }

    #pragma unroll
    for (int reg = 0; reg < 4; reg++) {
        int gr = qt*64 + w*16 + quad*4 + reg;
        if (gr < N_) {
            float inv = 1.0f / l_run[reg];
            #pragma unroll
            for (int nj = 0; nj < 4; nj++)
                ctxp[((size_t)(b*N_ + gr))*C_ + h*64 + nj*16 + r16] = ctx[nj][reg] * inv;
        }
    }
}

// ---------------------------------------------------------------------------
// cls fp64 path, re-sharded.
// 1) q0[b,h,d] = 0.125 * x0[b,:].Wq[h*64+d,:]  -- one wave per output.
// ---------------------------------------------------------------------------
__global__ __launch_bounds__(256) void cls_q0_kernel(
    const float* __restrict__ x, const float* __restrict__ w_qkv,
    double* __restrict__ dws)
{
    const int t = threadIdx.x;
    const int wg = blockIdx.x * 4 + (t >> 6);     // 0..3071
    const int lane = t & 63;
    const int b = wg / 768, rem = wg - b * 768;   // rem = h*64+d = Wq row
    const float* x0 = x + (size_t)b * N_ * C_;
    const float* wr = w_qkv + (size_t)rem * C_;
    double s = 0.0;
    #pragma unroll
    for (int i = 0; i < 12; i++) {
        int c = lane + i*64;
        s += (double)x0[c] * (double)wr[c];
    }
    #pragma unroll
    for (int o = 1; o < 64; o <<= 1) s += __shfl_xor(s, o);
    if (lane == 0) dws[DQ0 + wg] = s * 0.125;
}

// 2) ms[b,h,c] = sum_d q0[b,h,d] * Wk[h*64+d, c]
__global__ __launch_bounds__(256) void cls_ms_kernel(
    const float* __restrict__ w_qkv, double* __restrict__ dws)
{
    __shared__ double q0s[64];
    const int t = threadIdx.x;
    const int c = blockIdx.x * 256 + t;
    const int h = blockIdx.y, b = blockIdx.z;
    if (t < 64) q0s[t] = dws[DQ0 + (b*H_ + h)*64 + t];
    __syncthreads();
    const float* wk = w_qkv + (size_t)(C_ + h*64) * C_ + c;
    double s = 0.0;
    #pragma unroll 8
    for (int d = 0; d < 64; d++) s += q0s[d] * (double)wk[(size_t)d * C_];
    dws[DMS + ((size_t)(b*H_ + h))*768 + c] = s;
}

// 3) lg[b,h,j] = x[b,j,:].ms[b,h,:] -- one block per (j,b); 4 waves x 3 heads.
__global__ __launch_bounds__(256) void cls_logits_kernel(
    const float* __restrict__ x, double* __restrict__ dws)
{
    __shared__ double xs[768];
    const int j = blockIdx.x, b = blockIdx.y;
    const int t = threadIdx.x;
    const int w = t >> 6, lane = t & 63;
    const float* xr = x + ((size_t)b * N_ + j) * C_;
    for (int c = t; c < C_; c += 256) xs[c] = (double)xr[c];
    __syncthreads();
    for (int hh = 0; hh < 3; hh++) {
        int h = w + hh * 4;
        const double* ms = dws + DMS + ((size_t)(b*H_ + h))*768;
        double s = 0.0;
        #pragma unroll
        for (int i = 0; i < 12; i++) {
            int c = lane + i*64;
            s += xs[c] * ms[c];
        }
        #pragma unroll
        for (int o = 1; o < 64; o <<= 1) s += __shfl_xor(s, o);
        if (lane == 0) dws[DLG + ((size_t)(b*H_ + h))*1025 + j] = s;
    }
}

// 4) per-batch: softmax each head (fp64), mean over heads, bitonic top-k.
__global__ __launch_bounds__(256) void cls_topk_kernel(
    const double* __restrict__ dws, float* __restrict__ out)
{
    const int b = blockIdx.x;
    const int t = threadIdx.x;
    __shared__ double meanv[1024];
    __shared__ double ec[1025];
    __shared__ double red[256];
    __shared__ double sval[1024];
    __shared__ int    sidx[1024];

    for (int i = t; i < 1024; i += 256) meanv[i] = 0.0;
    __syncthreads();

    for (int h = 0; h < H_; h++) {
        const double* lg = dws + DLG + ((size_t)(b*H_ + h))*1025;
        double mloc = -1e300;
        for (int j = t; j < N_; j += 256) mloc = fmax(mloc, lg[j]);
        red[t] = mloc; __syncthreads();
        for (int o = 128; o > 0; o >>= 1) {
            if (t < o) red[t] = fmax(red[t], red[t+o]);
            __syncthreads();
        }
        double mx = red[0]; __syncthreads();
        double sloc = 0.0;
        for (int j = t; j < N_; j += 256) { double e = exp(lg[j] - mx); ec[j] = e; sloc += e; }
        red[t] = sloc; __syncthreads();
        for (int o = 128; o > 0; o >>= 1) {
            if (t < o) red[t] += red[t+o];
            __syncthreads();
        }
        double Z = red[0]; __syncthreads();
        for (int j = t; j < N_; j += 256)
            if (j >= 1) meanv[j-1] += ec[j] / Z;   // same-thread ec read, no race
        __syncthreads();
    }

    for (int i = t; i < 1024; i += 256) {
        double v = meanv[i] / 12.0;
        meanv[i] = v;
        out[OFF_CLS + (size_t)b*1024 + i] = (float)v;
    }

    for (int pass = 0; pass < 2; pass++) {
        const bool desc = (pass == 0);
        __syncthreads();
        for (int i = t; i < 1024; i += 256) { sval[i] = meanv[i]; sidx[i] = i; }
        for (int k = 2; k <= 1024; k <<= 1) {
            for (int j = k >> 1; j > 0; j >>= 1) {
                __syncthreads();
                for (int i = t; i < 1024; i += 256) {
                    int l = i ^ j;
                    if (l > i) {
                        double av = sval[i], bv = sval[l];
                        int    ai = sidx[i], bi = sidx[l];
                        bool before = desc ? (av > bv || (av == bv && ai < bi))
                                           : (av < bv || (av == bv && ai < bi));
                        bool up = ((i & k) == 0);
                        if (up ? !before : before) {
                            sval[i] = bv; sval[l] = av;
                            sidx[i] = bi; sidx[l] = ai;
                        }
                    }
                }
            }
        }
        __syncthreads();
        const size_t idx_off = desc ? (size_t)OFF_EIDX : (size_t)OFF_FIDX;
        const size_t ind_off = desc ? (size_t)OFF_EIND : (size_t)OFF_FIND;
        if (t < 103) out[idx_off + (size_t)b*103 + t] = (float)sidx[t];
        for (int u = t*4; u < 103*768; u += 1024) {
            int e = u / 768;
            float fv = (float)sidx[e];
            *(float4*)&out[ind_off + (size_t)b*103*768 + u] = make_float4(fv, fv, fv, fv);
        }
    }
}

// ---------------------------------------------------------------------------
extern "C" void kernel_launch(void* const* d_in, const int* in_sizes, int n_in,
                              void* d_out, int out_size, void* d_ws, size_t ws_size,
                              hipStream_t stream)
{
    const float* x     = (const float*)d_in[0];
    const float* w_qkv = (const float*)d_in[1];
    const float* w_out = (const float*)d_in[2];
    const float* b_out = (const float*)d_in[3];
    float* out = (float*)d_out;
    float* ws  = (float*)d_ws;

    float*  q    = ws + WS_Q;
    float*  k    = ws + WS_K;
    float*  v    = ws + WS_V;
    float*  ctx  = ws + WS_CTX;
    double* dws  = (double*)(ws + WS_F64);
    unsigned short* xs   = (unsigned short*)(ws + WS_XS);
    unsigned short* qkvB = (unsigned short*)(ws + WS_QKVB);
    unsigned short* outB = (unsigned short*)(ws + WS_OUTB);

    split_a_kernel<<<(M_PAD*192 + 255)/256, 256, 0, stream>>>(x, xs, M_TOT, M_PAD);
    split_b_kernel<<<(2304*192 + 255)/256, 256, 0, stream>>>(w_qkv, qkvB, 2304);
    split_b_kernel<<<(768*192 + 255)/256, 256, 0, stream>>>(w_out, outB, 768);

    gemm_qkv_kernel<<<dim3(18, 33), 256, 0, stream>>>(xs, qkvB, q, k, v);
    attn_kernel<<<dim3(17, H_, B_), 256, 0, stream>>>(q, k, v, ctx);

    // cls fp64 path (re-sharded)
    cls_q0_kernel<<<768, 256, 0, stream>>>(x, w_qkv, dws);
    cls_ms_kernel<<<dim3(3, H_, B_), 256, 0, stream>>>(w_qkv, dws);
    cls_logits_kernel<<<dim3(N_, B_), 256, 0, stream>>>(x, dws);
    cls_topk_kernel<<<B_, 256, 0, stream>>>(dws, out);

    split_a_kernel<<<(M_PAD*192 + 255)/256, 256, 0, stream>>>(ctx, xs, M_TOT, M_PAD);
    gemm_out_kernel<<<dim3(6, 33), 256, 0, stream>>>(xs, outB, b_out, out);
}

// Round 6
// 568.304 us; speedup vs baseline: 1.6649x; 1.0380x over previous
//
#include <hip/hip_runtime.h>

// ---------------------------------------------------------------------------
// SABlock round 6: attention de-overheaded.
//  - gemm_qkv epilogue emits q/k/v already as bf16 hi/lo in MFMA-ready
//    layouts: qe/ke[b,h,n,(hi d0..63 | lo 64..127)], vt[b,h,(d|64+d),n]
//    (pre-transposed), n padded to 1088. No fp32 q/k/v anywhere.
//  - attn stages tiles with pure uint4 copies (no f2bf, no transpose).
//  - attn epilogue writes ctx directly in split-A' ushort pattern
//    ([hi|hi|lo], K=2304) -> second split_a kernel removed.
// GEMMs: split-bf16 MFMA. cls/topk: fp64 re-sharded (round 5, passing).
//
// d_out layout (flat f32): out@0, enh_index@3148800, enh_idx@3465216,
//   fuse_index@3465628, fuse_idx@3782044, cls_attn@3782456
// ---------------------------------------------------------------------------

#define B_  4
#define N_  1025
#define C_  768
#define H_  12
#define D_  64
#define M_TOT (B_ * N_)      // 4100
#define M_PAD 4224           // 33 * 128
#define KEXP 2304            // 3 * 768
#define NPAD 1088            // 17 * 64

#define OFF_EIND 3148800
#define OFF_EIDX 3465216
#define OFF_FIND 3465628
#define OFF_FIDX 3782044
#define OFF_CLS  3782456

// workspace offsets (floats); high water 18628608 f = 74.5 MB
#define WS_F64   0           // double region (196608 floats = 98304 doubles)
#define WS_XS    196608      // ushort[4224*2304]  x' A-pattern; later ctx'
#define WS_QKVB  5062656     // ushort[2304*2304]  (B' of w_qkv)
#define WS_OUTB  7716864     // ushort[768*2304]   (B' of w_out)
#define WS_QE    8601600     // ushort[4*12*1088*128]
#define WS_KE    11943936
#define WS_VT    15286272

// double-region layout (indices into double*)
#define DQ0 0                // [4*12*64]
#define DMS 3072             // [4*12*768]
#define DLG 39936            // [4*12*1025]

typedef short s16x8 __attribute__((ext_vector_type(8)));
typedef float f32x4 __attribute__((ext_vector_type(4)));

__device__ inline unsigned short f2bf(float f) {
    unsigned u = __float_as_uint(f);
    u += 0x7FFF + ((u >> 16) & 1);          // RNE to bf16
    return (unsigned short)(u >> 16);
}
__device__ inline float bf2f(unsigned short h) {
    return __uint_as_float(((unsigned)h) << 16);
}

// ---------------------------------------------------------------------------
// Splitters
// ---------------------------------------------------------------------------
__global__ __launch_bounds__(256) void split_a_kernel(
    const float* __restrict__ src, unsigned short* __restrict__ dst,
    int M, int Mpad)
{
    int idx = blockIdx.x * 256 + threadIdx.x;
    int m = idx / 192, c4 = (idx - m * 192) * 4;
    if (m >= Mpad) return;
    ushort4 hi = make_ushort4(0,0,0,0), lo = hi;
    if (m < M) {
        float4 f = *(const float4*)&src[(size_t)m * C_ + c4];
        hi.x = f2bf(f.x); hi.y = f2bf(f.y); hi.z = f2bf(f.z); hi.w = f2bf(f.w);
        lo.x = f2bf(f.x - bf2f(hi.x)); lo.y = f2bf(f.y - bf2f(hi.y));
        lo.z = f2bf(f.z - bf2f(hi.z)); lo.w = f2bf(f.w - bf2f(hi.w));
    }
    unsigned short* d = dst + (size_t)m * KEXP + c4;
    *(ushort4*)(d)        = hi;
    *(ushort4*)(d + 768)  = hi;
    *(ushort4*)(d + 1536) = lo;
}

__global__ __launch_bounds__(256) void split_b_kernel(
    const float* __restrict__ src, unsigned short* __restrict__ dst, int M)
{
    int idx = blockIdx.x * 256 + threadIdx.x;
    int m = idx / 192, c4 = (idx - m * 192) * 4;
    if (m >= M) return;
    float4 f = *(const float4*)&src[(size_t)m * C_ + c4];
    ushort4 hi, lo;
    hi.x = f2bf(f.x); hi.y = f2bf(f.y); hi.z = f2bf(f.z); hi.w = f2bf(f.w);
    lo.x = f2bf(f.x - bf2f(hi.x)); lo.y = f2bf(f.y - bf2f(hi.y));
    lo.z = f2bf(f.z - bf2f(hi.z)); lo.w = f2bf(f.w - bf2f(hi.w));
    unsigned short* d = dst + (size_t)m * KEXP + c4;
    *(ushort4*)(d)        = hi;
    *(ushort4*)(d + 768)  = lo;
    *(ushort4*)(d + 1536) = hi;
}

// ---------------------------------------------------------------------------
// gemm_qkv: C = A'.B'^T; epilogue converts each element to bf16 hi/lo and
// scatters into qe/ke (row layout, hi|lo halves) or vt (transposed planes).
// ---------------------------------------------------------------------------
__global__ __launch_bounds__(256) void gemm_qkv_kernel(
    const unsigned short* __restrict__ A, const unsigned short* __restrict__ Bm,
    unsigned short* __restrict__ qe, unsigned short* __restrict__ ke,
    unsigned short* __restrict__ vtp)
{
    __shared__ unsigned short As[128][40];
    __shared__ unsigned short Bs[128][40];
    const int n0 = blockIdx.x * 128;
    const int m0 = blockIdx.y * 128;
    const int t = threadIdx.x;
    const int lane = t & 63, wv = t >> 6;
    const int wr = wv >> 1, wc = wv & 1;
    const int q4 = lane >> 4, r = lane & 15;
    const int srow = t >> 2, scol = (t & 3) * 8;

    f32x4 acc[4][4];
    #pragma unroll
    for (int i = 0; i < 4; i++)
        #pragma unroll
        for (int j = 0; j < 4; j++)
            #pragma unroll
            for (int e = 0; e < 4; e++) acc[i][j][e] = 0.f;

    const unsigned short* a0p = A  + (size_t)(m0 + srow) * KEXP + scol;
    const unsigned short* b0p = Bm + (size_t)(n0 + srow) * KEXP + scol;

    for (int kb = 0; kb < KEXP; kb += 32) {
        uint4 va0 = *(const uint4*)(a0p + kb);
        uint4 va1 = *(const uint4*)(a0p + kb + (size_t)64 * KEXP);
        uint4 vb0 = *(const uint4*)(b0p + kb);
        uint4 vb1 = *(const uint4*)(b0p + kb + (size_t)64 * KEXP);
        __syncthreads();
        *(uint4*)&As[srow][scol]      = va0;
        *(uint4*)&As[srow + 64][scol] = va1;
        *(uint4*)&Bs[srow][scol]      = vb0;
        *(uint4*)&Bs[srow + 64][scol] = vb1;
        __syncthreads();
        s16x8 af[4], bfr[4];
        #pragma unroll
        for (int i = 0; i < 4; i++) {
            af[i]  = *(const s16x8*)&As[wr*64 + i*16 + r][q4*8];
            bfr[i] = *(const s16x8*)&Bs[wc*64 + i*16 + r][q4*8];
        }
        #pragma unroll
        for (int i = 0; i < 4; i++)
            #pragma unroll
            for (int j = 0; j < 4; j++)
                acc[i][j] = __builtin_amdgcn_mfma_f32_16x16x32_bf16(af[i], bfr[j], acc[i][j], 0, 0, 0);
    }

    const int sel = n0 / C_;
    const int off = n0 % C_;
    const float scl = (sel == 0) ? 0.125f : 1.0f;
    #pragma unroll
    for (int i = 0; i < 4; i++) {
        #pragma unroll
        for (int rr = 0; rr < 4; rr++) {
            int gm = m0 + wr*64 + i*16 + q4*4 + rr;
            if (gm < M_TOT) {
                int bb = gm / N_, n = gm - bb * N_;
                #pragma unroll
                for (int j = 0; j < 4; j++) {
                    int col = off + wc*64 + j*16 + r;
                    int h = col >> 6, d = col & 63;
                    float val = acc[i][j][rr] * scl;
                    unsigned short hi = f2bf(val);
                    unsigned short lo = f2bf(val - bf2f(hi));
                    size_t bh = (size_t)(bb*H_ + h);
                    if (sel <= 1) {
                        unsigned short* dst = (sel == 0 ? qe : ke) + (bh*NPAD + n)*128;
                        dst[d]      = hi;
                        dst[64 + d] = lo;
                    } else {
                        unsigned short* dst = vtp + bh*128*NPAD;
                        dst[(size_t)d*NPAD + n]        = hi;
                        dst[(size_t)(64 + d)*NPAD + n] = lo;
                    }
                }
            }
        }
    }
}

__global__ __launch_bounds__(256) void gemm_out_kernel(
    const unsigned short* __restrict__ A, const unsigned short* __restrict__ Bm,
    const float* __restrict__ bias, float* __restrict__ out)
{
    __shared__ unsigned short As[128][40];
    __shared__ unsigned short Bs[128][40];
    const int n0 = blockIdx.x * 128;
    const int m0 = blockIdx.y * 128;
    const int t = threadIdx.x;
    const int lane = t & 63, wv = t >> 6;
    const int wr = wv >> 1, wc = wv & 1;
    const int q4 = lane >> 4, r = lane & 15;
    const int srow = t >> 2, scol = (t & 3) * 8;

    f32x4 acc[4][4];
    #pragma unroll
    for (int i = 0; i < 4; i++)
        #pragma unroll
        for (int j = 0; j < 4; j++)
            #pragma unroll
            for (int e = 0; e < 4; e++) acc[i][j][e] = 0.f;

    const unsigned short* a0p = A  + (size_t)(m0 + srow) * KEXP + scol;
    const unsigned short* b0p = Bm + (size_t)(n0 + srow) * KEXP + scol;

    for (int kb = 0; kb < KEXP; kb += 32) {
        uint4 va0 = *(const uint4*)(a0p + kb);
        uint4 va1 = *(const uint4*)(a0p + kb + (size_t)64 * KEXP);
        uint4 vb0 = *(const uint4*)(b0p + kb);
        uint4 vb1 = *(const uint4*)(b0p + kb + (size_t)64 * KEXP);
        __syncthreads();
        *(uint4*)&As[srow][scol]      = va0;
        *(uint4*)&As[srow + 64][scol] = va1;
        *(uint4*)&Bs[srow][scol]      = vb0;
        *(uint4*)&Bs[srow + 64][scol] = vb1;
        __syncthreads();
        s16x8 af[4], bfr[4];
        #pragma unroll
        for (int i = 0; i < 4; i++) {
            af[i]  = *(const s16x8*)&As[wr*64 + i*16 + r][q4*8];
            bfr[i] = *(const s16x8*)&Bs[wc*64 + i*16 + r][q4*8];
        }
        #pragma unroll
        for (int i = 0; i < 4; i++)
            #pragma unroll
            for (int j = 0; j < 4; j++)
                acc[i][j] = __builtin_amdgcn_mfma_f32_16x16x32_bf16(af[i], bfr[j], acc[i][j], 0, 0, 0);
    }

    #pragma unroll
    for (int i = 0; i < 4; i++) {
        #pragma unroll
        for (int rr = 0; rr < 4; rr++) {
            int gm = m0 + wr*64 + i*16 + q4*4 + rr;
            if (gm < M_TOT) {
                #pragma unroll
                for (int j = 0; j < 4; j++) {
                    int col = n0 + wc*64 + j*16 + r;
                    out[(size_t)gm * C_ + col] = acc[i][j][rr] + bias[col];
                }
            }
        }
    }
}

// ---------------------------------------------------------------------------
// MFMA flash attention; staging is pure uint4 copies from pre-built bf16
// layouts. Epilogue writes ctx' directly in split-A' ushort pattern.
// ---------------------------------------------------------------------------
__global__ __launch_bounds__(256) void attn_kernel(
    const unsigned short* __restrict__ qe, const unsigned short* __restrict__ ke,
    const unsigned short* __restrict__ vtp, unsigned short* __restrict__ ctxs)
{
    __shared__ unsigned short Qe[64][136];   // [qrow][Qh 0..63 | Ql 64..127]
    __shared__ unsigned short KP[64][136];   // A: [kvrow][Kh|Kl]; B: [qrow][Ph|Pl]
    __shared__ unsigned short Vt[64][136];   // [d][Vh^T n0..63 | Vl^T 64..127]

    const int qt = blockIdx.x, h = blockIdx.y, b = blockIdx.z;
    const int t = threadIdx.x;
    const int w = t >> 6, lane = t & 63;
    const int quad = lane >> 4, r16 = lane & 15;
    const int q8 = quad * 8;
    const size_t bh = (size_t)(b*H_ + h);

    {   // stage Q tile: rows qt*64.., 128 ushorts each
        const unsigned short* src = qe + (bh*NPAD + qt*64 + (t >> 2)) * 128;
        #pragma unroll
        for (int e = 0; e < 4; e++) {
            int c = ((t & 3) + 4*e) * 8;
            *(uint4*)&Qe[t >> 2][c] = *(const uint4*)(src + c);
        }
    }

    int qu;
    {
        int rlo = qt*64, rhi = min(qt*64 + 63, N_ - 1);
        if (rlo == 0) qu = -2;
        else { int b1 = (rlo-1)>>8, b2 = (rhi-1)>>8; qu = (b1==b2) ? b1 : -2; }
    }

    float m_run[4], l_run[4];
    f32x4 ctx[4];
    #pragma unroll
    for (int i = 0; i < 4; i++) {
        m_run[i] = -1e30f; l_run[i] = 0.f;
        #pragma unroll
        for (int e = 0; e < 4; e++) ctx[i][e] = 0.f;
    }

    for (int kt = 0; kt < 17; kt++) {
        if (qu >= 0 && kt > 0) {
            int clo = kt*64, chi = min(kt*64 + 63, N_ - 1);
            int b1 = (clo-1)>>8, b2 = (chi-1)>>8;
            if (b1 == b2 && b1 == qu) continue;
        }

        __syncthreads();
        {   // stage K tile
            const unsigned short* ksrc = ke + (bh*NPAD + kt*64 + (t >> 2)) * 128;
            #pragma unroll
            for (int e = 0; e < 4; e++) {
                int c = ((t & 3) + 4*e) * 8;
                *(uint4*)&KP[t >> 2][c] = *(const uint4*)(ksrc + c);
            }
            // stage V^T tile: plane p (0..127), 64 ushorts at n=kt*64
            const int p = t >> 1;
            const unsigned short* vsrc = vtp + (bh*128 + p)*NPAD + kt*64;
            const int vd = p & 63, vseg = (p >> 6) * 64;
            #pragma unroll
            for (int e = 0; e < 4; e++) {
                int c = ((t & 1) + 2*e) * 8;
                *(uint4*)&Vt[vd][vseg + c] = *(const uint4*)(vsrc + c);
            }
        }
        __syncthreads();

        f32x4 st[4];
        #pragma unroll
        for (int j = 0; j < 4; j++)
            #pragma unroll
            for (int e = 0; e < 4; e++) st[j][e] = 0.f;
        {
            const int ar = w*16 + r16;
            s16x8 ah0 = *(const s16x8*)&Qe[ar][q8];
            s16x8 ah1 = *(const s16x8*)&Qe[ar][32 + q8];
            s16x8 al0 = *(const s16x8*)&Qe[ar][64 + q8];
            s16x8 al1 = *(const s16x8*)&Qe[ar][96 + q8];
            #pragma unroll
            for (int j = 0; j < 4; j++) {
                const int br = j*16 + r16;
                s16x8 bh0 = *(const s16x8*)&KP[br][q8];
                s16x8 bh1 = *(const s16x8*)&KP[br][32 + q8];
                s16x8 bl0 = *(const s16x8*)&KP[br][64 + q8];
                s16x8 bl1 = *(const s16x8*)&KP[br][96 + q8];
                st[j] = __builtin_amdgcn_mfma_f32_16x16x32_bf16(ah0, bh0, st[j], 0,0,0);
                st[j] = __builtin_amdgcn_mfma_f32_16x16x32_bf16(ah1, bh1, st[j], 0,0,0);
                st[j] = __builtin_amdgcn_mfma_f32_16x16x32_bf16(ah0, bl0, st[j], 0,0,0);
                st[j] = __builtin_amdgcn_mfma_f32_16x16x32_bf16(ah1, bl1, st[j], 0,0,0);
                st[j] = __builtin_amdgcn_mfma_f32_16x16x32_bf16(al0, bh0, st[j], 0,0,0);
                st[j] = __builtin_amdgcn_mfma_f32_16x16x32_bf16(al1, bh1, st[j], 0,0,0);
            }
        }

        float pv[4][4];
        float alpha[4];
        #pragma unroll
        for (int reg = 0; reg < 4; reg++) {
            int gr = qt*64 + w*16 + quad*4 + reg;
            int qb = (gr >= 1) ? ((gr - 1) >> 8) : -1;
            float mx = -1e30f;
            float vv[4];
            #pragma unroll
            for (int j = 0; j < 4; j++) {
                int gc = kt*64 + j*16 + r16;
                bool ok = (gr < N_) && (gc < N_) &&
                          !((gr >= 1) && (gc >= 1) && (((gc - 1) >> 8) == qb));
                vv[j] = ok ? st[j][reg] : -1e30f;
                mx = fmaxf(mx, vv[j]);
            }
            mx = fmaxf(mx, __shfl_xor(mx, 1));
            mx = fmaxf(mx, __shfl_xor(mx, 2));
            mx = fmaxf(mx, __shfl_xor(mx, 4));
            mx = fmaxf(mx, __shfl_xor(mx, 8));
            float mnew = fmaxf(m_run[reg], mx);
            alpha[reg] = __expf(m_run[reg] - mnew);
            m_run[reg] = mnew;
            float ps = 0.f;
            #pragma unroll
            for (int j = 0; j < 4; j++) {
                float p = (vv[j] > -1e29f) ? __expf(vv[j] - mnew) : 0.f;
                pv[reg][j] = p; ps += p;
            }
            ps += __shfl_xor(ps, 1);
            ps += __shfl_xor(ps, 2);
            ps += __shfl_xor(ps, 4);
            ps += __shfl_xor(ps, 8);
            l_run[reg] = l_run[reg] * alpha[reg] + ps;
        }

        __syncthreads();   // all waves done reading K from KP

        #pragma unroll
        for (int reg = 0; reg < 4; reg++) {
            int lrow = w*16 + quad*4 + reg;
            #pragma unroll
            for (int j = 0; j < 4; j++) {
                float p = pv[reg][j];
                unsigned short ph = f2bf(p);
                unsigned short pl = f2bf(p - bf2f(ph));
                KP[lrow][j*16 + r16]      = ph;
                KP[lrow][64 + j*16 + r16] = pl;
            }
        }

        #pragma unroll
        for (int nj = 0; nj < 4; nj++)
            #pragma unroll
            for (int reg = 0; reg < 4; reg++)
                ctx[nj][reg] *= alpha[reg];

        {
            const int ar = w*16 + r16;
            s16x8 ph0 = *(const s16x8*)&KP[ar][q8];
            s16x8 ph1 = *(const s16x8*)&KP[ar][32 + q8];
            s16x8 pl0 = *(const s16x8*)&KP[ar][64 + q8];
            s16x8 pl1 = *(const s16x8*)&KP[ar][96 + q8];
            #pragma unroll
            for (int nj = 0; nj < 4; nj++) {
                const int br = nj*16 + r16;
                s16x8 vh0 = *(const s16x8*)&Vt[br][q8];
                s16x8 vh1 = *(const s16x8*)&Vt[br][32 + q8];
                s16x8 vl0 = *(const s16x8*)&Vt[br][64 + q8];
                s16x8 vl1 = *(const s16x8*)&Vt[br][96 + q8];
                ctx[nj] = __builtin_amdgcn_mfma_f32_16x16x32_bf16(ph0, vh0, ctx[nj], 0,0,0);
                ctx[nj] = __builtin_amdgcn_mfma_f32_16x16x32_bf16(ph1, vh1, ctx[nj], 0,0,0);
                ctx[nj] = __builtin_amdgcn_mfma_f32_16x16x32_bf16(ph0, vl0, ctx[nj], 0,0,0);
                ctx[nj] = __builtin_amdgcn_mfma_f32_16x16x32_bf16(ph1, vl1, ctx[nj], 0,0,0);
                ctx[nj] = __builtin_amdgcn_mfma_f32_16x16x32_bf16(pl0, vh0, ctx[nj], 0,0,0);
                ctx[nj] = __builtin_amdgcn_mfma_f32_16x16x32_bf16(pl1, vh1, ctx[nj], 0,0,0);
            }
        }
    }

    // epilogue: ctx/l -> ctx' in split-A' pattern ([hi|hi|lo], row = token)
    #pragma unroll
    for (int reg = 0; reg < 4; reg++) {
        int gr = qt*64 + w*16 + quad*4 + reg;
        if (gr < N_) {
            float inv = 1.0f / l_run[reg];
            size_t row = (size_t)(b*N_ + gr) * KEXP;
            #pragma unroll
            for (int nj = 0; nj < 4; nj++) {
                float val = ctx[nj][reg] * inv;
                unsigned short hi = f2bf(val);
                unsigned short lo = f2bf(val - bf2f(hi));
                int c = h*64 + nj*16 + r16;
                ctxs[row + c]        = hi;
                ctxs[row + 768 + c]  = hi;
                ctxs[row + 1536 + c] = lo;
            }
        }
    }
}

// ---------------------------------------------------------------------------
// cls fp64 path (round 5, passing).
// ---------------------------------------------------------------------------
__global__ __launch_bounds__(256) void cls_q0_kernel(
    const float* __restrict__ x, const float* __restrict__ w_qkv,
    double* __restrict__ dws)
{
    const int t = threadIdx.x;
    const int wg = blockIdx.x * 4 + (t >> 6);
    const int lane = t & 63;
    const int b = wg / 768, rem = wg - b * 768;
    const float* x0 = x + (size_t)b * N_ * C_;
    const float* wr = w_qkv + (size_t)rem * C_;
    double s = 0.0;
    #pragma unroll
    for (int i = 0; i < 12; i++) {
        int c = lane + i*64;
        s += (double)x0[c] * (double)wr[c];
    }
    #pragma unroll
    for (int o = 1; o < 64; o <<= 1) s += __shfl_xor(s, o);
    if (lane == 0) dws[DQ0 + wg] = s * 0.125;
}

__global__ __launch_bounds__(256) void cls_ms_kernel(
    const float* __restrict__ w_qkv, double* __restrict__ dws)
{
    __shared__ double q0s[64];
    const int t = threadIdx.x;
    const int c = blockIdx.x * 256 + t;
    const int h = blockIdx.y, b = blockIdx.z;
    if (t < 64) q0s[t] = dws[DQ0 + (b*H_ + h)*64 + t];
    __syncthreads();
    const float* wk = w_qkv + (size_t)(C_ + h*64) * C_ + c;
    double s = 0.0;
    #pragma unroll 8
    for (int d = 0; d < 64; d++) s += q0s[d] * (double)wk[(size_t)d * C_];
    dws[DMS + ((size_t)(b*H_ + h))*768 + c] = s;
}

__global__ __launch_bounds__(256) void cls_logits_kernel(
    const float* __restrict__ x, double* __restrict__ dws)
{
    __shared__ double xs[768];
    const int j = blockIdx.x, b = blockIdx.y;
    const int t = threadIdx.x;
    const int w = t >> 6, lane = t & 63;
    const float* xr = x + ((size_t)b * N_ + j) * C_;
    for (int c = t; c < C_; c += 256) xs[c] = (double)xr[c];
    __syncthreads();
    for (int hh = 0; hh < 3; hh++) {
        int h = w + hh * 4;
        const double* ms = dws + DMS + ((size_t)(b*H_ + h))*768;
        double s = 0.0;
        #pragma unroll
        for (int i = 0; i < 12; i++) {
            int c = lane + i*64;
            s += xs[c] * ms[c];
        }
        #pragma unroll
        for (int o = 1; o < 64; o <<= 1) s += __shfl_xor(s, o);
        if (lane == 0) dws[DLG + ((size_t)(b*H_ + h))*1025 + j] = s;
    }
}

__global__ __launch_bounds__(256) void cls_topk_kernel(
    const double* __restrict__ dws, float* __restrict__ out)
{
    const int b = blockIdx.x;
    const int t = threadIdx.x;
    __shared__ double meanv[1024];
    __shared__ double ec[1025];
    __shared__ double red[256];
    __shared__ double sval[1024];
    __shared__ int    sidx[1024];

    for (int i = t; i < 1024; i += 256) meanv[i] = 0.0;
    __syncthreads();

    for (int h = 0; h < H_; h++) {
        const double* lg = dws + DLG + ((size_t)(b*H_ + h))*1025;
        double mloc = -1e300;
        for (int j = t; j < N_; j += 256) mloc = fmax(mloc, lg[j]);
        red[t] = mloc; __syncthreads();
        for (int o = 128; o > 0; o >>= 1) {
            if (t < o) red[t] = fmax(red[t], red[t+o]);
            __syncthreads();
        }
        double mx = red[0]; __syncthreads();
        double sloc = 0.0;
        for (int j = t; j < N_; j += 256) { double e = exp(lg[j] - mx); ec[j] = e; sloc += e; }
        red[t] = sloc; __syncthreads();
        for (int o = 128; o > 0; o >>= 1) {
            if (t < o) red[t] += red[t+o];
            __syncthreads();
        }
        double Z = red[0]; __syncthreads();
        for (int j = t; j < N_; j += 256)
            if (j >= 1) meanv[j-1] += ec[j] / Z;
        __syncthreads();
    }

    for (int i = t; i < 1024; i += 256) {
        double v = meanv[i] / 12.0;
        meanv[i] = v;
        out[OFF_CLS + (size_t)b*1024 + i] = (float)v;
    }

    for (int pass = 0; pass < 2; pass++) {
        const bool desc = (pass == 0);
        __syncthreads();
        for (int i = t; i < 1024; i += 256) { sval[i] = meanv[i]; sidx[i] = i; }
        for (int k = 2; k <= 1024; k <<= 1) {
            for (int j = k >> 1; j > 0; j >>= 1) {
                __syncthreads();
                for (int i = t; i < 1024; i += 256) {
                    int l = i ^ j;
                    if (l > i) {
                        double av = sval[i], bv = sval[l];
                        int    ai = sidx[i], bi = sidx[l];
                        bool before = desc ? (av > bv || (av == bv && ai < bi))
                                           : (av < bv || (av == bv && ai < bi));
                        bool up = ((i & k) == 0);
                        if (up ? !before : before) {
                            sval[i] = bv; sval[l] = av;
                            sidx[i] = bi; sidx[l] = ai;
                        }
                    }
                }
            }
        }
        __syncthreads();
        const size_t idx_off = desc ? (size_t)OFF_EIDX : (size_t)OFF_FIDX;
        const size_t ind_off = desc ? (size_t)OFF_EIND : (size_t)OFF_FIND;
        if (t < 103) out[idx_off + (size_t)b*103 + t] = (float)sidx[t];
        for (int u = t*4; u < 103*768; u += 1024) {
            int e = u / 768;
            float fv = (float)sidx[e];
            *(float4*)&out[ind_off + (size_t)b*103*768 + u] = make_float4(fv, fv, fv, fv);
        }
    }
}

// ---------------------------------------------------------------------------
extern "C" void kernel_launch(void* const* d_in, const int* in_sizes, int n_in,
                              void* d_out, int out_size, void* d_ws, size_t ws_size,
                              hipStream_t stream)
{
    const float* x     = (const float*)d_in[0];
    const float* w_qkv = (const float*)d_in[1];
    const float* w_out = (const float*)d_in[2];
    const float* b_out = (const float*)d_in[3];
    float* out = (float*)d_out;
    float* ws  = (float*)d_ws;

    double* dws = (double*)(ws + WS_F64);
    unsigned short* xs   = (unsigned short*)(ws + WS_XS);   // x'; later ctx'
    unsigned short* qkvB = (unsigned short*)(ws + WS_QKVB);
    unsigned short* outB = (unsigned short*)(ws + WS_OUTB);
    unsigned short* qe   = (unsigned short*)(ws + WS_QE);
    unsigned short* ke   = (unsigned short*)(ws + WS_KE);
    unsigned short* vtp  = (unsigned short*)(ws + WS_VT);

    split_a_kernel<<<(M_PAD*192 + 255)/256, 256, 0, stream>>>(x, xs, M_TOT, M_PAD);
    split_b_kernel<<<(2304*192 + 255)/256, 256, 0, stream>>>(w_qkv, qkvB, 2304);
    split_b_kernel<<<(768*192 + 255)/256, 256, 0, stream>>>(w_out, outB, 768);

    gemm_qkv_kernel<<<dim3(18, 33), 256, 0, stream>>>(xs, qkvB, qe, ke, vtp);
    attn_kernel<<<dim3(17, H_, B_), 256, 0, stream>>>(qe, ke, vtp, xs);

    cls_q0_kernel<<<768, 256, 0, stream>>>(x, w_qkv, dws);
    cls_ms_kernel<<<dim3(3, H_, B_), 256, 0, stream>>>(w_qkv, dws);
    cls_logits_kernel<<<dim3(N_, B_), 256, 0, stream>>>(x, dws);
    cls_topk_kernel<<<B_, 256, 0, stream>>>(dws, out);

    gemm_out_kernel<<<dim3(6, 33), 256, 0, stream>>>(xs, outB, b_out, out);
}

// Round 7
// 513.962 us; speedup vs baseline: 1.8409x; 1.1057x over previous
//
#include <hip/hip_runtime.h>

// ---------------------------------------------------------------------------
// SABlock round 7: sort-based top-k (161 us, 4 blocks, ~350 barriers)
// replaced by rank-by-counting (cls_reduce + cls_final, ~10 us total).
// GEMMs + attention: split-bf16 MFMA (rounds 3-6, passing).
// cls softmax path: fp64 (exact index ordering).
//
// d_out layout (flat f32): out@0, enh_index@3148800, enh_idx@3465216,
//   fuse_index@3465628, fuse_idx@3782044, cls_attn@3782456
// ---------------------------------------------------------------------------

#define B_  4
#define N_  1025
#define C_  768
#define H_  12
#define D_  64
#define M_TOT (B_ * N_)      // 4100
#define M_PAD 4224           // 33 * 128
#define KEXP 2304            // 3 * 768
#define NPAD 1088            // 17 * 64

#define OFF_EIND 3148800
#define OFF_EIDX 3465216
#define OFF_FIND 3465628
#define OFF_FIDX 3782044
#define OFF_CLS  3782456

// workspace offsets (floats); high water 18628608 f = 74.5 MB
#define WS_F64   0           // double region (196608 floats = 98304 doubles)
#define WS_XS    196608      // ushort[4224*2304]  x' A-pattern; later ctx'
#define WS_QKVB  5062656     // ushort[2304*2304]  (B' of w_qkv)
#define WS_OUTB  7716864     // ushort[768*2304]   (B' of w_out)
#define WS_QE    8601600     // ushort[4*12*1088*128]
#define WS_KE    11943936
#define WS_VT    15286272

// double-region layout (indices into double*)
#define DQ0 0                // [4*12*64]
#define DMS 3072             // [4*12*768]
#define DLG 39936            // [4*12*1025]
#define DMX 89136            // [4*12] per-(b,h) max
#define DZ  89184            // [4*12] per-(b,h) Z    (total 89232 < 98304)

typedef short s16x8 __attribute__((ext_vector_type(8)));
typedef float f32x4 __attribute__((ext_vector_type(4)));

__device__ inline unsigned short f2bf(float f) {
    unsigned u = __float_as_uint(f);
    u += 0x7FFF + ((u >> 16) & 1);          // RNE to bf16
    return (unsigned short)(u >> 16);
}
__device__ inline float bf2f(unsigned short h) {
    return __uint_as_float(((unsigned)h) << 16);
}

// ---------------------------------------------------------------------------
// Splitters
// ---------------------------------------------------------------------------
__global__ __launch_bounds__(256) void split_a_kernel(
    const float* __restrict__ src, unsigned short* __restrict__ dst,
    int M, int Mpad)
{
    int idx = blockIdx.x * 256 + threadIdx.x;
    int m = idx / 192, c4 = (idx - m * 192) * 4;
    if (m >= Mpad) return;
    ushort4 hi = make_ushort4(0,0,0,0), lo = hi;
    if (m < M) {
        float4 f = *(const float4*)&src[(size_t)m * C_ + c4];
        hi.x = f2bf(f.x); hi.y = f2bf(f.y); hi.z = f2bf(f.z); hi.w = f2bf(f.w);
        lo.x = f2bf(f.x - bf2f(hi.x)); lo.y = f2bf(f.y - bf2f(hi.y));
        lo.z = f2bf(f.z - bf2f(hi.z)); lo.w = f2bf(f.w - bf2f(hi.w));
    }
    unsigned short* d = dst + (size_t)m * KEXP + c4;
    *(ushort4*)(d)        = hi;
    *(ushort4*)(d + 768)  = hi;
    *(ushort4*)(d + 1536) = lo;
}

__global__ __launch_bounds__(256) void split_b_kernel(
    const float* __restrict__ src, unsigned short* __restrict__ dst, int M)
{
    int idx = blockIdx.x * 256 + threadIdx.x;
    int m = idx / 192, c4 = (idx - m * 192) * 4;
    if (m >= M) return;
    float4 f = *(const float4*)&src[(size_t)m * C_ + c4];
    ushort4 hi, lo;
    hi.x = f2bf(f.x); hi.y = f2bf(f.y); hi.z = f2bf(f.z); hi.w = f2bf(f.w);
    lo.x = f2bf(f.x - bf2f(hi.x)); lo.y = f2bf(f.y - bf2f(hi.y));
    lo.z = f2bf(f.z - bf2f(hi.z)); lo.w = f2bf(f.w - bf2f(hi.w));
    unsigned short* d = dst + (size_t)m * KEXP + c4;
    *(ushort4*)(d)        = hi;
    *(ushort4*)(d + 768)  = lo;
    *(ushort4*)(d + 1536) = hi;
}

// ---------------------------------------------------------------------------
// gemm_qkv (round 6, passing): epilogue emits bf16 hi/lo MFMA-ready layouts.
// ---------------------------------------------------------------------------
__global__ __launch_bounds__(256) void gemm_qkv_kernel(
    const unsigned short* __restrict__ A, const unsigned short* __restrict__ Bm,
    unsigned short* __restrict__ qe, unsigned short* __restrict__ ke,
    unsigned short* __restrict__ vtp)
{
    __shared__ unsigned short As[128][40];
    __shared__ unsigned short Bs[128][40];
    const int n0 = blockIdx.x * 128;
    const int m0 = blockIdx.y * 128;
    const int t = threadIdx.x;
    const int lane = t & 63, wv = t >> 6;
    const int wr = wv >> 1, wc = wv & 1;
    const int q4 = lane >> 4, r = lane & 15;
    const int srow = t >> 2, scol = (t & 3) * 8;

    f32x4 acc[4][4];
    #pragma unroll
    for (int i = 0; i < 4; i++)
        #pragma unroll
        for (int j = 0; j < 4; j++)
            #pragma unroll
            for (int e = 0; e < 4; e++) acc[i][j][e] = 0.f;

    const unsigned short* a0p = A  + (size_t)(m0 + srow) * KEXP + scol;
    const unsigned short* b0p = Bm + (size_t)(n0 + srow) * KEXP + scol;

    for (int kb = 0; kb < KEXP; kb += 32) {
        uint4 va0 = *(const uint4*)(a0p + kb);
        uint4 va1 = *(const uint4*)(a0p + kb + (size_t)64 * KEXP);
        uint4 vb0 = *(const uint4*)(b0p + kb);
        uint4 vb1 = *(const uint4*)(b0p + kb + (size_t)64 * KEXP);
        __syncthreads();
        *(uint4*)&As[srow][scol]      = va0;
        *(uint4*)&As[srow + 64][scol] = va1;
        *(uint4*)&Bs[srow][scol]      = vb0;
        *(uint4*)&Bs[srow + 64][scol] = vb1;
        __syncthreads();
        s16x8 af[4], bfr[4];
        #pragma unroll
        for (int i = 0; i < 4; i++) {
            af[i]  = *(const s16x8*)&As[wr*64 + i*16 + r][q4*8];
            bfr[i] = *(const s16x8*)&Bs[wc*64 + i*16 + r][q4*8];
        }
        #pragma unroll
        for (int i = 0; i < 4; i++)
            #pragma unroll
            for (int j = 0; j < 4; j++)
                acc[i][j] = __builtin_amdgcn_mfma_f32_16x16x32_bf16(af[i], bfr[j], acc[i][j], 0, 0, 0);
    }

    const int sel = n0 / C_;
    const int off = n0 % C_;
    const float scl = (sel == 0) ? 0.125f : 1.0f;
    #pragma unroll
    for (int i = 0; i < 4; i++) {
        #pragma unroll
        for (int rr = 0; rr < 4; rr++) {
            int gm = m0 + wr*64 + i*16 + q4*4 + rr;
            if (gm < M_TOT) {
                int bb = gm / N_, n = gm - bb * N_;
                #pragma unroll
                for (int j = 0; j < 4; j++) {
                    int col = off + wc*64 + j*16 + r;
                    int h = col >> 6, d = col & 63;
                    float val = acc[i][j][rr] * scl;
                    unsigned short hi = f2bf(val);
                    unsigned short lo = f2bf(val - bf2f(hi));
                    size_t bh = (size_t)(bb*H_ + h);
                    if (sel <= 1) {
                        unsigned short* dst = (sel == 0 ? qe : ke) + (bh*NPAD + n)*128;
                        dst[d]      = hi;
                        dst[64 + d] = lo;
                    } else {
                        unsigned short* dst = vtp + bh*128*NPAD;
                        dst[(size_t)d*NPAD + n]        = hi;
                        dst[(size_t)(64 + d)*NPAD + n] = lo;
                    }
                }
            }
        }
    }
}

__global__ __launch_bounds__(256) void gemm_out_kernel(
    const unsigned short* __restrict__ A, const unsigned short* __restrict__ Bm,
    const float* __restrict__ bias, float* __restrict__ out)
{
    __shared__ unsigned short As[128][40];
    __shared__ unsigned short Bs[128][40];
    const int n0 = blockIdx.x * 128;
    const int m0 = blockIdx.y * 128;
    const int t = threadIdx.x;
    const int lane = t & 63, wv = t >> 6;
    const int wr = wv >> 1, wc = wv & 1;
    const int q4 = lane >> 4, r = lane & 15;
    const int srow = t >> 2, scol = (t & 3) * 8;

    f32x4 acc[4][4];
    #pragma unroll
    for (int i = 0; i < 4; i++)
        #pragma unroll
        for (int j = 0; j < 4; j++)
            #pragma unroll
            for (int e = 0; e < 4; e++) acc[i][j][e] = 0.f;

    const unsigned short* a0p = A  + (size_t)(m0 + srow) * KEXP + scol;
    const unsigned short* b0p = Bm + (size_t)(n0 + srow) * KEXP + scol;

    for (int kb = 0; kb < KEXP; kb += 32) {
        uint4 va0 = *(const uint4*)(a0p + kb);
        uint4 va1 = *(const uint4*)(a0p + kb + (size_t)64 * KEXP);
        uint4 vb0 = *(const uint4*)(b0p + kb);
        uint4 vb1 = *(const uint4*)(b0p + kb + (size_t)64 * KEXP);
        __syncthreads();
        *(uint4*)&As[srow][scol]      = va0;
        *(uint4*)&As[srow + 64][scol] = va1;
        *(uint4*)&Bs[srow][scol]      = vb0;
        *(uint4*)&Bs[srow + 64][scol] = vb1;
        __syncthreads();
        s16x8 af[4], bfr[4];
        #pragma unroll
        for (int i = 0; i < 4; i++) {
            af[i]  = *(const s16x8*)&As[wr*64 + i*16 + r][q4*8];
            bfr[i] = *(const s16x8*)&Bs[wc*64 + i*16 + r][q4*8];
        }
        #pragma unroll
        for (int i = 0; i < 4; i++)
            #pragma unroll
            for (int j = 0; j < 4; j++)
                acc[i][j] = __builtin_amdgcn_mfma_f32_16x16x32_bf16(af[i], bfr[j], acc[i][j], 0, 0, 0);
    }

    #pragma unroll
    for (int i = 0; i < 4; i++) {
        #pragma unroll
        for (int rr = 0; rr < 4; rr++) {
            int gm = m0 + wr*64 + i*16 + q4*4 + rr;
            if (gm < M_TOT) {
                #pragma unroll
                for (int j = 0; j < 4; j++) {
                    int col = n0 + wc*64 + j*16 + r;
                    out[(size_t)gm * C_ + col] = acc[i][j][rr] + bias[col];
                }
            }
        }
    }
}

// ---------------------------------------------------------------------------
// MFMA flash attention (round 6, passing).
// ---------------------------------------------------------------------------
__global__ __launch_bounds__(256) void attn_kernel(
    const unsigned short* __restrict__ qe, const unsigned short* __restrict__ ke,
    const unsigned short* __restrict__ vtp, unsigned short* __restrict__ ctxs)
{
    __shared__ unsigned short Qe[64][136];
    __shared__ unsigned short KP[64][136];
    __shared__ unsigned short Vt[64][136];

    const int qt = blockIdx.x, h = blockIdx.y, b = blockIdx.z;
    const int t = threadIdx.x;
    const int w = t >> 6, lane = t & 63;
    const int quad = lane >> 4, r16 = lane & 15;
    const int q8 = quad * 8;
    const size_t bh = (size_t)(b*H_ + h);

    {
        const unsigned short* src = qe + (bh*NPAD + qt*64 + (t >> 2)) * 128;
        #pragma unroll
        for (int e = 0; e < 4; e++) {
            int c = ((t & 3) + 4*e) * 8;
            *(uint4*)&Qe[t >> 2][c] = *(const uint4*)(src + c);
        }
    }

    int qu;
    {
        int rlo = qt*64, rhi = min(qt*64 + 63, N_ - 1);
        if (rlo == 0) qu = -2;
        else { int b1 = (rlo-1)>>8, b2 = (rhi-1)>>8; qu = (b1==b2) ? b1 : -2; }
    }

    float m_run[4], l_run[4];
    f32x4 ctx[4];
    #pragma unroll
    for (int i = 0; i < 4; i++) {
        m_run[i] = -1e30f; l_run[i] = 0.f;
        #pragma unroll
        for (int e = 0; e < 4; e++) ctx[i][e] = 0.f;
    }

    for (int kt = 0; kt < 17; kt++) {
        if (qu >= 0 && kt > 0) {
            int clo = kt*64, chi = min(kt*64 + 63, N_ - 1);
            int b1 = (clo-1)>>8, b2 = (chi-1)>>8;
            if (b1 == b2 && b1 == qu) continue;
        }

        __syncthreads();
        {
            const unsigned short* ksrc = ke + (bh*NPAD + kt*64 + (t >> 2)) * 128;
            #pragma unroll
            for (int e = 0; e < 4; e++) {
                int c = ((t & 3) + 4*e) * 8;
                *(uint4*)&KP[t >> 2][c] = *(const uint4*)(ksrc + c);
            }
            const int p = t >> 1;
            const unsigned short* vsrc = vtp + (bh*128 + p)*NPAD + kt*64;
            const int vd = p & 63, vseg = (p >> 6) * 64;
            #pragma unroll
            for (int e = 0; e < 4; e++) {
                int c = ((t & 1) + 2*e) * 8;
                *(uint4*)&Vt[vd][vseg + c] = *(const uint4*)(vsrc + c);
            }
        }
        __syncthreads();

        f32x4 st[4];
        #pragma unroll
        for (int j = 0; j < 4; j++)
            #pragma unroll
            for (int e = 0; e < 4; e++) st[j][e] = 0.f;
        {
            const int ar = w*16 + r16;
            s16x8 ah0 = *(const s16x8*)&Qe[ar][q8];
            s16x8 ah1 = *(const s16x8*)&Qe[ar][32 + q8];
            s16x8 al0 = *(const s16x8*)&Qe[ar][64 + q8];
            s16x8 al1 = *(const s16x8*)&Qe[ar][96 + q8];
            #pragma unroll
            for (int j = 0; j < 4; j++) {
                const int br = j*16 + r16;
                s16x8 bh0 = *(const s16x8*)&KP[br][q8];
                s16x8 bh1 = *(const s16x8*)&KP[br][32 + q8];
                s16x8 bl0 = *(const s16x8*)&KP[br][64 + q8];
                s16x8 bl1 = *(const s16x8*)&KP[br][96 + q8];
                st[j] = __builtin_amdgcn_mfma_f32_16x16x32_bf16(ah0, bh0, st[j], 0,0,0);
                st[j] = __builtin_amdgcn_mfma_f32_16x16x32_bf16(ah1, bh1, st[j], 0,0,0);
                st[j] = __builtin_amdgcn_mfma_f32_16x16x32_bf16(ah0, bl0, st[j], 0,0,0);
                st[j] = __builtin_amdgcn_mfma_f32_16x16x32_bf16(ah1, bl1, st[j], 0,0,0);
                st[j] = __builtin_amdgcn_mfma_f32_16x16x32_bf16(al0, bh0, st[j], 0,0,0);
                st[j] = __builtin_amdgcn_mfma_f32_16x16x32_bf16(al1, bh1, st[j], 0,0,0);
            }
        }

        float pv[4][4];
        float alpha[4];
        #pragma unroll
        for (int reg = 0; reg < 4; reg++) {
            int gr = qt*64 + w*16 + quad*4 + reg;
            int qb = (gr >= 1) ? ((gr - 1) >> 8) : -1;
            float mx = -1e30f;
            float vv[4];
            #pragma unroll
            for (int j = 0; j < 4; j++) {
                int gc = kt*64 + j*16 + r16;
                bool ok = (gr < N_) && (gc < N_) &&
                          !((gr >= 1) && (gc >= 1) && (((gc - 1) >> 8) == qb));
                vv[j] = ok ? st[j][reg] : -1e30f;
                mx = fmaxf(mx, vv[j]);
            }
            mx = fmaxf(mx, __shfl_xor(mx, 1));
            mx = fmaxf(mx, __shfl_xor(mx, 2));
            mx = fmaxf(mx, __shfl_xor(mx, 4));
            mx = fmaxf(mx, __shfl_xor(mx, 8));
            float mnew = fmaxf(m_run[reg], mx);
            alpha[reg] = __expf(m_run[reg] - mnew);
            m_run[reg] = mnew;
            float ps = 0.f;
            #pragma unroll
            for (int j = 0; j < 4; j++) {
                float p = (vv[j] > -1e29f) ? __expf(vv[j] - mnew) : 0.f;
                pv[reg][j] = p; ps += p;
            }
            ps += __shfl_xor(ps, 1);
            ps += __shfl_xor(ps, 2);
            ps += __shfl_xor(ps, 4);
            ps += __shfl_xor(ps, 8);
            l_run[reg] = l_run[reg] * alpha[reg] + ps;
        }

        __syncthreads();

        #pragma unroll
        for (int reg = 0; reg < 4; reg++) {
            int lrow = w*16 + quad*4 + reg;
            #pragma unroll
            for (int j = 0; j < 4; j++) {
                float p = pv[reg][j];
                unsigned short ph = f2bf(p);
                unsigned short pl = f2bf(p - bf2f(ph));
                KP[lrow][j*16 + r16]      = ph;
                KP[lrow][64 + j*16 + r16] = pl;
            }
        }

        #pragma unroll
        for (int nj = 0; nj < 4; nj++)
            #pragma unroll
            for (int reg = 0; reg < 4; reg++)
                ctx[nj][reg] *= alpha[reg];

        {
            const int ar = w*16 + r16;
            s16x8 ph0 = *(const s16x8*)&KP[ar][q8];
            s16x8 ph1 = *(const s16x8*)&KP[ar][32 + q8];
            s16x8 pl0 = *(const s16x8*)&KP[ar][64 + q8];
            s16x8 pl1 = *(const s16x8*)&KP[ar][96 + q8];
            #pragma unroll
            for (int nj = 0; nj < 4; nj++) {
                const int br = nj*16 + r16;
                s16x8 vh0 = *(const s16x8*)&Vt[br][q8];
                s16x8 vh1 = *(const s16x8*)&Vt[br][32 + q8];
                s16x8 vl0 = *(const s16x8*)&Vt[br][64 + q8];
                s16x8 vl1 = *(const s16x8*)&Vt[br][96 + q8];
                ctx[nj] = __builtin_amdgcn_mfma_f32_16x16x32_bf16(ph0, vh0, ctx[nj], 0,0,0);
                ctx[nj] = __builtin_amdgcn_mfma_f32_16x16x32_bf16(ph1, vh1, ctx[nj], 0,0,0);
                ctx[nj] = __builtin_amdgcn_mfma_f32_16x16x32_bf16(ph0, vl0, ctx[nj], 0,0,0);
                ctx[nj] = __builtin_amdgcn_mfma_f32_16x16x32_bf16(ph1, vl1, ctx[nj], 0,0,0);
                ctx[nj] = __builtin_amdgcn_mfma_f32_16x16x32_bf16(pl0, vh0, ctx[nj], 0,0,0);
                ctx[nj] = __builtin_amdgcn_mfma_f32_16x16x32_bf16(pl1, vh1, ctx[nj], 0,0,0);
            }
        }
    }

    #pragma unroll
    for (int reg = 0; reg < 4; reg++) {
        int gr = qt*64 + w*16 + quad*4 + reg;
        if (gr < N_) {
            float inv = 1.0f / l_run[reg];
            size_t row = (size_t)(b*N_ + gr) * KEXP;
            #pragma unroll
            for (int nj = 0; nj < 4; nj++) {
                float val = ctx[nj][reg] * inv;
                unsigned short hi = f2bf(val);
                unsigned short lo = f2bf(val - bf2f(hi));
                int c = h*64 + nj*16 + r16;
                ctxs[row + c]        = hi;
                ctxs[row + 768 + c]  = hi;
                ctxs[row + 1536 + c] = lo;
            }
        }
    }
}

// ---------------------------------------------------------------------------
// cls fp64 path: q0 / ms / logits (round 5, passing).
// ---------------------------------------------------------------------------
__global__ __launch_bounds__(256) void cls_q0_kernel(
    const float* __restrict__ x, const float* __restrict__ w_qkv,
    double* __restrict__ dws)
{
    const int t = threadIdx.x;
    const int wg = blockIdx.x * 4 + (t >> 6);
    const int lane = t & 63;
    const int b = wg / 768, rem = wg - b * 768;
    const float* x0 = x + (size_t)b * N_ * C_;
    const float* wr = w_qkv + (size_t)rem * C_;
    double s = 0.0;
    #pragma unroll
    for (int i = 0; i < 12; i++) {
        int c = lane + i*64;
        s += (double)x0[c] * (double)wr[c];
    }
    #pragma unroll
    for (int o = 1; o < 64; o <<= 1) s += __shfl_xor(s, o);
    if (lane == 0) dws[DQ0 + wg] = s * 0.125;
}

__global__ __launch_bounds__(256) void cls_ms_kernel(
    const float* __restrict__ w_qkv, double* __restrict__ dws)
{
    __shared__ double q0s[64];
    const int t = threadIdx.x;
    const int c = blockIdx.x * 256 + t;
    const int h = blockIdx.y, b = blockIdx.z;
    if (t < 64) q0s[t] = dws[DQ0 + (b*H_ + h)*64 + t];
    __syncthreads();
    const float* wk = w_qkv + (size_t)(C_ + h*64) * C_ + c;
    double s = 0.0;
    #pragma unroll 8
    for (int d = 0; d < 64; d++) s += q0s[d] * (double)wk[(size_t)d * C_];
    dws[DMS + ((size_t)(b*H_ + h))*768 + c] = s;
}

__global__ __launch_bounds__(256) void cls_logits_kernel(
    const float* __restrict__ x, double* __restrict__ dws)
{
    __shared__ double xs[768];
    const int j = blockIdx.x, b = blockIdx.y;
    const int t = threadIdx.x;
    const int w = t >> 6, lane = t & 63;
    const float* xr = x + ((size_t)b * N_ + j) * C_;
    for (int c = t; c < C_; c += 256) xs[c] = (double)xr[c];
    __syncthreads();
    for (int hh = 0; hh < 3; hh++) {
        int h = w + hh * 4;
        const double* ms = dws + DMS + ((size_t)(b*H_ + h))*768;
        double s = 0.0;
        #pragma unroll
        for (int i = 0; i < 12; i++) {
            int c = lane + i*64;
            s += xs[c] * ms[c];
        }
        #pragma unroll
        for (int o = 1; o < 64; o <<= 1) s += __shfl_xor(s, o);
        if (lane == 0) dws[DLG + ((size_t)(b*H_ + h))*1025 + j] = s;
    }
}

// ---------------------------------------------------------------------------
// cls_reduce: per-(b,h) softmax max and Z (fp64, same reduction tree order
// as the passing round-5 kernel: 256-way strided load + binary tree).
// ---------------------------------------------------------------------------
__global__ __launch_bounds__(256) void cls_reduce_kernel(
    const double* __restrict__ dwsr, double* __restrict__ dws)
{
    __shared__ double red[256];
    const int h = blockIdx.x, b = blockIdx.y;
    const int t = threadIdx.x;
    const double* lg = dwsr + DLG + ((size_t)(b*H_ + h))*1025;
    double mloc = -1e300;
    for (int j = t; j < N_; j += 256) mloc = fmax(mloc, lg[j]);
    red[t] = mloc; __syncthreads();
    for (int o = 128; o > 0; o >>= 1) {
        if (t < o) red[t] = fmax(red[t], red[t+o]);
        __syncthreads();
    }
    double mx = red[0]; __syncthreads();
    double sloc = 0.0;
    for (int j = t; j < N_; j += 256) sloc += exp(lg[j] - mx);
    red[t] = sloc; __syncthreads();
    for (int o = 128; o > 0; o >>= 1) {
        if (t < o) red[t] += red[t+o];
        __syncthreads();
    }
    if (t == 0) {
        dws[DMX + b*H_ + h] = mx;
        dws[DZ  + b*H_ + h] = red[0];
    }
}

// ---------------------------------------------------------------------------
// cls_final: thread i owns token i+1. meanv_i = (1/12) sum_h exp(lg-mx)/Z;
// rank-by-counting under both comparators (identical to stable sort order);
// scatter idx lists + broadcasts. 1024 threads, 4 blocks, ~4 barriers.
// ---------------------------------------------------------------------------
__global__ __launch_bounds__(1024) void cls_final_kernel(
    const double* __restrict__ dws, float* __restrict__ out)
{
    __shared__ double mv[1024];
    __shared__ int eidx[104], fidx[104];
    const int b = blockIdx.x;
    const int t = threadIdx.x;        // 0..1023 = token t+1

    double s = 0.0;
    #pragma unroll
    for (int h = 0; h < H_; h++) {
        double mx = dws[DMX + b*H_ + h];
        double Z  = dws[DZ  + b*H_ + h];
        double lg = dws[DLG + ((size_t)(b*H_ + h))*1025 + (t + 1)];
        s += exp(lg - mx) / Z;
    }
    s *= (1.0 / 12.0);
    mv[t] = s;
    out[OFF_CLS + (size_t)b*1024 + t] = (float)s;
    __syncthreads();

    int cd = 0, ca = 0;
    const double v = s;
    for (int j = 0; j < 1024; j++) {
        double u = mv[j];
        bool tie = (u == v) && (j < t);
        cd += (u > v) || tie;
        ca += (u < v) || tie;
    }
    if (cd < 103) eidx[cd] = t;
    if (ca < 103) fidx[ca] = t;
    __syncthreads();

    if (t < 103) {
        out[OFF_EIDX + (size_t)b*103 + t] = (float)eidx[t];
        out[OFF_FIDX + (size_t)b*103 + t] = (float)fidx[t];
    }
    for (int u4 = t*4; u4 < 103*768; u4 += 4096) {
        int e = u4 / 768;
        float ev = (float)eidx[e], fv = (float)fidx[e];
        *(float4*)&out[OFF_EIND + (size_t)b*103*768 + u4] = make_float4(ev, ev, ev, ev);
        *(float4*)&out[OFF_FIND + (size_t)b*103*768 + u4] = make_float4(fv, fv, fv, fv);
    }
}

// ---------------------------------------------------------------------------
extern "C" void kernel_launch(void* const* d_in, const int* in_sizes, int n_in,
                              void* d_out, int out_size, void* d_ws, size_t ws_size,
                              hipStream_t stream)
{
    const float* x     = (const float*)d_in[0];
    const float* w_qkv = (const float*)d_in[1];
    const float* w_out = (const float*)d_in[2];
    const float* b_out = (const float*)d_in[3];
    float* out = (float*)d_out;
    float* ws  = (float*)d_ws;

    double* dws = (double*)(ws + WS_F64);
    unsigned short* xs   = (unsigned short*)(ws + WS_XS);   // x'; later ctx'
    unsigned short* qkvB = (unsigned short*)(ws + WS_QKVB);
    unsigned short* outB = (unsigned short*)(ws + WS_OUTB);
    unsigned short* qe   = (unsigned short*)(ws + WS_QE);
    unsigned short* ke   = (unsigned short*)(ws + WS_KE);
    unsigned short* vtp  = (unsigned short*)(ws + WS_VT);

    split_a_kernel<<<(M_PAD*192 + 255)/256, 256, 0, stream>>>(x, xs, M_TOT, M_PAD);
    split_b_kernel<<<(2304*192 + 255)/256, 256, 0, stream>>>(w_qkv, qkvB, 2304);
    split_b_kernel<<<(768*192 + 255)/256, 256, 0, stream>>>(w_out, outB, 768);

    gemm_qkv_kernel<<<dim3(18, 33), 256, 0, stream>>>(xs, qkvB, qe, ke, vtp);
    attn_kernel<<<dim3(17, H_, B_), 256, 0, stream>>>(qe, ke, vtp, xs);

    cls_q0_kernel<<<768, 256, 0, stream>>>(x, w_qkv, dws);
    cls_ms_kernel<<<dim3(3, H_, B_), 256, 0, stream>>>(w_qkv, dws);
    cls_logits_kernel<<<dim3(N_, B_), 256, 0, stream>>>(x, dws);
    cls_reduce_kernel<<<dim3(H_, B_), 256, 0, stream>>>(dws, dws);
    cls_final_kernel<<<B_, 1024, 0, stream>>>(dws, out);

    gemm_out_kernel<<<dim3(6, 33), 256, 0, stream>>>(xs, outB, b_out, out);
}